// Round 3
// baseline (1948.316 us; speedup 1.0000x reference)
//
#include <hip/hip_runtime.h>

#define N_NODES 262144
#define N_EDGES 2097152
#define EPS_BN 1e-5f

// Monotone float<->uint encoding: preserves order, 0 is a sentinel below everything.
__device__ __forceinline__ unsigned enc(float f) {
    unsigned u = __float_as_uint(f);
    return (u & 0x80000000u) ? ~u : (u | 0x80000000u);
}
__device__ __forceinline__ float dec(unsigned u) {
    unsigned b = (u & 0x80000000u) ? (u & 0x7FFFFFFFu) : ~u;
    return __uint_as_float(b);
}

// ---- CSR build ----

__global__ __launch_bounds__(256) void hist_k(const int* __restrict__ ei,
                                              int* __restrict__ deg) {
    int e = blockIdx.x * 256 + threadIdx.x;
    int d = ei[N_EDGES + e];
    atomicAdd(&deg[d], 1);
}

__global__ __launch_bounds__(256) void scan_block_sums(const int* __restrict__ deg,
                                                       int* __restrict__ bsum) {
    __shared__ int s[256];
    int t = threadIdx.x;
    s[t] = deg[blockIdx.x * 256 + t];
    __syncthreads();
    for (int off = 128; off > 0; off >>= 1) {
        if (t < off) s[t] += s[t + off];
        __syncthreads();
    }
    if (t == 0) bsum[blockIdx.x] = s[0];
}

__global__ __launch_bounds__(1024) void scan_top(const int* __restrict__ bsum,
                                                 int* __restrict__ boff) {
    __shared__ int s[1024];
    int t = threadIdx.x;
    int orig = bsum[t];
    s[t] = orig;
    __syncthreads();
    for (int off = 1; off < 1024; off <<= 1) {
        int v = (t >= off) ? s[t - off] : 0;
        __syncthreads();
        s[t] += v;
        __syncthreads();
    }
    boff[t] = s[t] - orig;   // exclusive
}

__global__ __launch_bounds__(256) void scan_final(const int* __restrict__ deg,
                                                  const int* __restrict__ boff,
                                                  int* __restrict__ offs,
                                                  int* __restrict__ cursor) {
    __shared__ int s[256];
    int t = threadIdx.x;
    int i = blockIdx.x * 256 + t;
    int v = deg[i];
    s[t] = v;
    __syncthreads();
    for (int off = 1; off < 256; off <<= 1) {
        int a = (t >= off) ? s[t - off] : 0;
        __syncthreads();
        s[t] += a;
        __syncthreads();
    }
    int ex = boff[blockIdx.x] + s[t] - v;
    offs[i] = ex;
    cursor[i] = ex;
}

__global__ __launch_bounds__(256) void scatter_k(const int* __restrict__ ei,
                                                 int* __restrict__ cursor,
                                                 int* __restrict__ csr_src) {
    int e = blockIdx.x * 256 + threadIdx.x;
    int s = ei[e];
    int d = ei[N_EDGES + e];
    int p = atomicAdd(&cursor[d], 1);
    csr_src[p] = s;
}

// pack [pos3, x] per node into one float4 for conv1's single-line gather
__global__ __launch_bounds__(256) void pack_px(const float* __restrict__ pos,
                                               const float* __restrict__ x,
                                               float4* __restrict__ px4) {
    int i = blockIdx.x * 256 + threadIdx.x;
    px4[i] = make_float4(pos[3*i], pos[3*i+1], pos[3*i+2], x[i]);
}

// ---- conv1: per-dst max over messages (1+3 -> 16), fused BN+ReLU.
// Writes rec[d] = [pos3, h1[16], pad] (32 floats, 128-B aligned record).
__global__ __launch_bounds__(256) void conv1_csr(
    const float4* __restrict__ px4,
    const int* __restrict__ offs, const int* __restrict__ cursor,
    const int* __restrict__ csr_src,
    const float* __restrict__ W1, const float* __restrict__ b1,
    const float* __restrict__ mean, const float* __restrict__ var,
    const float* __restrict__ gamma, const float* __restrict__ beta,
    float* __restrict__ rec)
{
    __shared__ float w[64], bs[16], scale[16], shift[16];
    if (threadIdx.x < 64) w[threadIdx.x] = W1[threadIdx.x];
    if (threadIdx.x < 16) {
        bs[threadIdx.x] = b1[threadIdx.x];
        float sc = gamma[threadIdx.x] * rsqrtf(var[threadIdx.x] + EPS_BN);
        scale[threadIdx.x] = sc;
        shift[threadIdx.x] = beta[threadIdx.x] - mean[threadIdx.x] * sc;
    }
    __syncthreads();
    int d = blockIdx.x * 256 + threadIdx.x;
    int start = offs[d], end = cursor[d];
    float4 me = px4[d];
    float acc[16];
#pragma unroll
    for (int f = 0; f < 16; ++f) acc[f] = -INFINITY;
    for (int j = start; j < end; ++j) {
        int s = csr_src[j];
        float4 p = px4[s];
        float xs = p.w;
        float rx = p.x - me.x, ry = p.y - me.y, rz = p.z - me.z;
#pragma unroll
        for (int f = 0; f < 16; ++f) {
            float m = bs[f] + xs*w[f] + rx*w[16+f] + ry*w[32+f] + rz*w[48+f];
            acc[f] = fmaxf(acc[f], m);
        }
    }
    bool any = end > start;
    float y[16];
#pragma unroll
    for (int f = 0; f < 16; ++f) {
        float v = any ? acc[f] : 0.0f;
        y[f] = fmaxf(v * scale[f] + shift[f], 0.0f);
    }
    float4* r4 = (float4*)(rec + (size_t)d * 32);
    r4[0] = make_float4(me.x, me.y, me.z, y[0]);
    r4[1] = make_float4(y[1], y[2], y[3], y[4]);
    r4[2] = make_float4(y[5], y[6], y[7], y[8]);
    r4[3] = make_float4(y[9], y[10], y[11], y[12]);
    r4[4] = make_float4(y[13], y[14], y[15], 0.0f);
}

// ---- conv2 + voxel pool fused: 2 threads per node, 16 channels each ----
__global__ __launch_bounds__(256, 4) void conv2_csr_pool(
    const float* __restrict__ rec,
    const int* __restrict__ offs, const int* __restrict__ cursor,
    const int* __restrict__ csr_src,
    const float* __restrict__ W2, const float* __restrict__ b2,
    const float* __restrict__ mean, const float* __restrict__ var,
    const float* __restrict__ gamma, const float* __restrict__ beta,
    unsigned* __restrict__ pool)
{
    __shared__ float w[608], bs[32], scale[32], shift[32];
    __shared__ unsigned lpool[2048];
    for (int i = threadIdx.x; i < 608; i += 256) w[i] = W2[i];
    if (threadIdx.x < 32) {
        bs[threadIdx.x] = b2[threadIdx.x];
        float sc = gamma[threadIdx.x] * rsqrtf(var[threadIdx.x] + EPS_BN);
        scale[threadIdx.x] = sc;
        shift[threadIdx.x] = beta[threadIdx.x] - mean[threadIdx.x] * sc;
    }
    for (int i = threadIdx.x; i < 2048; i += 256) lpool[i] = 0u;
    __syncthreads();

    int t = blockIdx.x * 256 + threadIdx.x;
    int d = t >> 1;
    int half = t & 1;          // channels [half*16, half*16+16)
    int cbase = half * 16;
    int start = offs[d], end = cursor[d];
    const float4* myr = (const float4*)(rec + (size_t)d * 32);
    float4 me = myr[0];        // pos in .x .y .z
    float acc[16];
#pragma unroll
    for (int i = 0; i < 16; ++i) acc[i] = -INFINITY;
    for (int j = start; j < end; ++j) {
        int s = csr_src[j];
        const float4* r4 = (const float4*)(rec + (size_t)s * 32);
        float4 r0 = r4[0], r1 = r4[1], r2 = r4[2], r3 = r4[3], r4v = r4[4];
        float rx = r0.x - me.x, ry = r0.y - me.y, rz = r0.z - me.z;
        float h[16] = {r0.w, r1.x, r1.y, r1.z, r1.w, r2.x, r2.y, r2.z,
                       r2.w, r3.x, r3.y, r3.z, r3.w, r4v.x, r4v.y, r4v.z};
        float msg[16];
#pragma unroll
        for (int i = 0; i < 16; ++i) {
            int c = cbase + i;
            msg[i] = bs[c] + rx*w[16*32+c] + ry*w[17*32+c] + rz*w[18*32+c];
        }
#pragma unroll
        for (int k = 0; k < 16; ++k)
#pragma unroll
            for (int i = 0; i < 16; ++i)
                msg[i] += h[k] * w[k*32 + cbase + i];
#pragma unroll
        for (int i = 0; i < 16; ++i) acc[i] = fmaxf(acc[i], msg[i]);
    }
    bool any = end > start;
    int gx = (int)floorf(me.x * (1.0f/16.0f));
    int gy = (int)floorf(me.y * (1.0f/16.0f));
    int c = min(max(gx + gy*8, 0), 63);
#pragma unroll
    for (int i = 0; i < 16; ++i) {
        int f = cbase + i;
        float v = any ? acc[i] : 0.0f;
        float y = fmaxf(v * scale[f] + shift[f], 0.0f);
        atomicMax(&lpool[c*32 + f], enc(y));
    }
    __syncthreads();
    // flush: skip atomics that cannot improve (stale reads are <= current: safe)
    for (int i = threadIdx.x; i < 2048; i += 256) {
        unsigned u = lpool[i];
        if (u > pool[i]) atomicMax(&pool[i], u);
    }
}

__global__ __launch_bounds__(256) void pool_decode(const unsigned* __restrict__ pool,
                                                   float* __restrict__ out) {
    int i = blockIdx.x * 256 + threadIdx.x;   // 2048
    unsigned u = pool[i];
    out[i] = (u == 0u) ? 0.0f : dec(u);
}

extern "C" void kernel_launch(void* const* d_in, const int* in_sizes, int n_in,
                              void* d_out, int out_size, void* d_ws, size_t ws_size,
                              hipStream_t stream) {
    const float* x    = (const float*)d_in[0];
    const float* pos  = (const float*)d_in[1];
    const int*   ei   = (const int*)d_in[2];
    const float* W1   = (const float*)d_in[3];
    const float* b1   = (const float*)d_in[4];
    const float* bn1m = (const float*)d_in[5];
    const float* bn1v = (const float*)d_in[6];
    const float* bn1w = (const float*)d_in[7];
    const float* bn1b = (const float*)d_in[8];
    const float* W2   = (const float*)d_in[9];
    const float* b2   = (const float*)d_in[10];
    const float* bn2m = (const float*)d_in[11];
    const float* bn2v = (const float*)d_in[12];
    const float* bn2w = (const float*)d_in[13];
    const float* bn2b = (const float*)d_in[14];

    int* deg       = (int*)d_ws;                      // N   (zeroed)
    unsigned* pool = (unsigned*)(deg + N_NODES);      // 2048 (zeroed)
    int* offs      = (int*)(pool + 2048);             // N
    int* cursor    = offs + N_NODES;                  // N
    int* csr_src   = cursor + N_NODES;                // E = 8N
    float* px4     = (float*)(csr_src + N_EDGES);     // 4N
    float* rec     = px4 + (size_t)N_NODES * 4;       // 32N (128-B aligned records)
    int* bsum      = (int*)(rec + (size_t)N_NODES*32); // 1024
    int* boff      = bsum + 1024;                     // 1024

    hipMemsetAsync(d_ws, 0, (size_t)(N_NODES + 2048) * 4, stream);

    hist_k         <<<N_EDGES/256, 256, 0, stream>>>(ei, deg);
    pack_px        <<<N_NODES/256, 256, 0, stream>>>(pos, x, (float4*)px4);
    scan_block_sums<<<N_NODES/256, 256, 0, stream>>>(deg, bsum);
    scan_top       <<<1, 1024, 0, stream>>>(bsum, boff);
    scan_final     <<<N_NODES/256, 256, 0, stream>>>(deg, boff, offs, cursor);
    scatter_k      <<<N_EDGES/256, 256, 0, stream>>>(ei, cursor, csr_src);
    conv1_csr      <<<N_NODES/256, 256, 0, stream>>>((const float4*)px4, offs, cursor, csr_src,
                                                     W1, b1, bn1m, bn1v, bn1w, bn1b, rec);
    conv2_csr_pool <<<N_NODES*2/256, 256, 0, stream>>>(rec, offs, cursor, csr_src,
                                                       W2, b2, bn2m, bn2v, bn2w, bn2b, pool);
    pool_decode    <<<8, 256, 0, stream>>>(pool, (float*)d_out);
}

// Round 4
// 1607.969 us; speedup vs baseline: 1.2117x; 1.2117x over previous
//
#include <hip/hip_runtime.h>

#define N_NODES 262144
#define N_EDGES 2097152
#define EPS_BN 1e-5f

// Monotone float<->uint encoding: preserves order, 0 is a sentinel below everything.
__device__ __forceinline__ unsigned enc(float f) {
    unsigned u = __float_as_uint(f);
    return (u & 0x80000000u) ? ~u : (u | 0x80000000u);
}
__device__ __forceinline__ float dec(unsigned u) {
    unsigned b = (u & 0x80000000u) ? (u & 0x7FFFFFFFu) : ~u;
    return __uint_as_float(b);
}

// ---- CSR build ----

__global__ __launch_bounds__(256) void hist_k(const int* __restrict__ ei,
                                              int* __restrict__ deg) {
    int e = blockIdx.x * 256 + threadIdx.x;
    int d = ei[N_EDGES + e];
    atomicAdd(&deg[d], 1);
}

__global__ __launch_bounds__(256) void scan_block_sums(const int* __restrict__ deg,
                                                       int* __restrict__ bsum) {
    __shared__ int s[256];
    int t = threadIdx.x;
    s[t] = deg[blockIdx.x * 256 + t];
    __syncthreads();
    for (int off = 128; off > 0; off >>= 1) {
        if (t < off) s[t] += s[t + off];
        __syncthreads();
    }
    if (t == 0) bsum[blockIdx.x] = s[0];
}

__global__ __launch_bounds__(1024) void scan_top(const int* __restrict__ bsum,
                                                 int* __restrict__ boff) {
    __shared__ int s[1024];
    int t = threadIdx.x;
    int orig = bsum[t];
    s[t] = orig;
    __syncthreads();
    for (int off = 1; off < 1024; off <<= 1) {
        int v = (t >= off) ? s[t - off] : 0;
        __syncthreads();
        s[t] += v;
        __syncthreads();
    }
    boff[t] = s[t] - orig;   // exclusive
}

__global__ __launch_bounds__(256) void scan_final(const int* __restrict__ deg,
                                                  const int* __restrict__ boff,
                                                  int* __restrict__ offs,
                                                  int* __restrict__ cursor) {
    __shared__ int s[256];
    int t = threadIdx.x;
    int i = blockIdx.x * 256 + t;
    int v = deg[i];
    s[t] = v;
    __syncthreads();
    for (int off = 1; off < 256; off <<= 1) {
        int a = (t >= off) ? s[t - off] : 0;
        __syncthreads();
        s[t] += a;
        __syncthreads();
    }
    int ex = boff[blockIdx.x] + s[t] - v;
    offs[i] = ex;
    cursor[i] = ex;
}

__global__ __launch_bounds__(256) void scatter_k(const int* __restrict__ ei,
                                                 int* __restrict__ cursor,
                                                 int* __restrict__ csr_src) {
    int e = blockIdx.x * 256 + threadIdx.x;
    int s = ei[e];
    int d = ei[N_EDGES + e];
    int p = atomicAdd(&cursor[d], 1);
    csr_src[p] = s;
}

// ---- degree sort (counting sort into 64 bins) ----

__global__ __launch_bounds__(256) void dhist_k(const int* __restrict__ deg,
                                               int* __restrict__ dhist) {
    __shared__ int hh[64];
    if (threadIdx.x < 64) hh[threadIdx.x] = 0;
    __syncthreads();
    int i = blockIdx.x * 256 + threadIdx.x;
    int b = min(deg[i], 63);
    atomicAdd(&hh[b], 1);
    __syncthreads();
    if (threadIdx.x < 64 && hh[threadIdx.x])
        atomicAdd(&dhist[threadIdx.x], hh[threadIdx.x]);
}

__global__ __launch_bounds__(64) void dscan_k(const int* __restrict__ dhist,
                                              int* __restrict__ dcur) {
    __shared__ int s[64];
    int t = threadIdx.x;
    int v = dhist[t];
    s[t] = v;
    __syncthreads();
    for (int off = 1; off < 64; off <<= 1) {
        int a = (t >= off) ? s[t - off] : 0;
        __syncthreads();
        s[t] += a;
        __syncthreads();
    }
    dcur[t] = s[t] - v;   // exclusive
}

__global__ __launch_bounds__(256) void dscatter_k(const int* __restrict__ deg,
                                                  int* __restrict__ dcur,
                                                  int* __restrict__ order) {
    __shared__ int cnt[64], base[64];
    if (threadIdx.x < 64) cnt[threadIdx.x] = 0;
    __syncthreads();
    int i = blockIdx.x * 256 + threadIdx.x;
    int b = min(deg[i], 63);
    int lr = atomicAdd(&cnt[b], 1);
    __syncthreads();
    if (threadIdx.x < 64 && cnt[threadIdx.x])
        base[threadIdx.x] = atomicAdd(&dcur[threadIdx.x], cnt[threadIdx.x]);
    __syncthreads();
    order[base[b] + lr] = i;
}

// pack [pos3, x] per node into one float4 for conv1's single-line gather
__global__ __launch_bounds__(256) void pack_px(const float* __restrict__ pos,
                                               const float* __restrict__ x,
                                               float4* __restrict__ px4) {
    int i = blockIdx.x * 256 + threadIdx.x;
    px4[i] = make_float4(pos[3*i], pos[3*i+1], pos[3*i+2], x[i]);
}

// ---- conv1: per-dst max (1+3 -> 16), fused BN+ReLU. rec[d] = [pos3, h1[16], pad] ----
__global__ __launch_bounds__(256) void conv1_csr(
    const float4* __restrict__ px4,
    const int* __restrict__ offs, const int* __restrict__ cursor,
    const int* __restrict__ csr_src, const int* __restrict__ order,
    const float* __restrict__ W1, const float* __restrict__ b1,
    const float* __restrict__ mean, const float* __restrict__ var,
    const float* __restrict__ gamma, const float* __restrict__ beta,
    float* __restrict__ rec)
{
    // w1T row f (8 floats): [w_x, w_rx, w_ry, w_rz, bias, pad, pad, pad]
    __shared__ float w1T[128], scale[16], shift[16];
    if (threadIdx.x < 128) {
        int f = threadIdx.x >> 3, k = threadIdx.x & 7;
        float v = 0.0f;
        if (k < 4) v = W1[k * 16 + f];
        else if (k == 4) v = b1[f];
        w1T[threadIdx.x] = v;
    }
    if (threadIdx.x < 16) {
        float sc = gamma[threadIdx.x] * rsqrtf(var[threadIdx.x] + EPS_BN);
        scale[threadIdx.x] = sc;
        shift[threadIdx.x] = beta[threadIdx.x] - mean[threadIdx.x] * sc;
    }
    __syncthreads();
    int d = order[blockIdx.x * 256 + threadIdx.x];
    int start = offs[d], end = cursor[d];
    float4 me = px4[d];
    float acc[16];
#pragma unroll
    for (int f = 0; f < 16; ++f) acc[f] = -INFINITY;
    for (int j = start; j < end; ++j) {
        int s = csr_src[j];
        float4 p = px4[s];
        float xs = p.w;
        float rx = p.x - me.x, ry = p.y - me.y, rz = p.z - me.z;
#pragma unroll
        for (int f = 0; f < 16; ++f) {
            const float4 wa = *(const float4*)&w1T[f * 8];
            float bias = w1T[f * 8 + 4];
            float m = bias + xs * wa.x + rx * wa.y + ry * wa.z + rz * wa.w;
            acc[f] = fmaxf(acc[f], m);
        }
    }
    bool any = end > start;
    float y[16];
#pragma unroll
    for (int f = 0; f < 16; ++f) {
        float v = any ? acc[f] : 0.0f;
        y[f] = fmaxf(v * scale[f] + shift[f], 0.0f);
    }
    float4* r4 = (float4*)(rec + (size_t)d * 32);
    r4[0] = make_float4(me.x, me.y, me.z, y[0]);
    r4[1] = make_float4(y[1], y[2], y[3], y[4]);
    r4[2] = make_float4(y[5], y[6], y[7], y[8]);
    r4[3] = make_float4(y[9], y[10], y[11], y[12]);
    r4[4] = make_float4(y[13], y[14], y[15], 0.0f);
}

// ---- conv2 + voxel pool fused: 1 thread/node, channel-at-a-time (no big msg array) ----
__global__ __launch_bounds__(256) void conv2_csr_pool(
    const float* __restrict__ rec,
    const int* __restrict__ offs, const int* __restrict__ cursor,
    const int* __restrict__ csr_src, const int* __restrict__ order,
    const float* __restrict__ W2, const float* __restrict__ b2,
    const float* __restrict__ mean, const float* __restrict__ var,
    const float* __restrict__ gamma, const float* __restrict__ beta,
    unsigned* __restrict__ pool)
{
    // wT row f (20 floats): [w_h0..w_h15, w_rx, w_ry, w_rz, bias]
    __shared__ float wT[640], scale[32], shift[32];
    __shared__ unsigned lpool[2048];
    for (int i = threadIdx.x; i < 640; i += 256) {
        int f = i / 20, k = i % 20;
        wT[i] = (k < 19) ? W2[k * 32 + f] : b2[f];
    }
    if (threadIdx.x < 32) {
        float sc = gamma[threadIdx.x] * rsqrtf(var[threadIdx.x] + EPS_BN);
        scale[threadIdx.x] = sc;
        shift[threadIdx.x] = beta[threadIdx.x] - mean[threadIdx.x] * sc;
    }
    for (int i = threadIdx.x; i < 2048; i += 256) lpool[i] = 0u;
    __syncthreads();

    int d = order[blockIdx.x * 256 + threadIdx.x];
    int start = offs[d], end = cursor[d];
    const float4* myr = (const float4*)(rec + (size_t)d * 32);
    float4 me = myr[0];        // pos in .x .y .z
    float acc[32];
#pragma unroll
    for (int f = 0; f < 32; ++f) acc[f] = -INFINITY;
    for (int j = start; j < end; ++j) {
        int s = csr_src[j];
        const float4* r4 = (const float4*)(rec + (size_t)s * 32);
        float4 r0 = r4[0], r1 = r4[1], r2 = r4[2], r3 = r4[3], rv = r4[4];
        float rx = r0.x - me.x, ry = r0.y - me.y, rz = r0.z - me.z;
#pragma unroll
        for (int f = 0; f < 32; ++f) {
            const float4* wf = (const float4*)&wT[f * 20];
            float4 w0 = wf[0], w1 = wf[1], w2 = wf[2], w3 = wf[3], w4 = wf[4];
            float m = w4.w + rx * w4.x + ry * w4.y + rz * w4.z;
            m += r0.w * w0.x + r1.x * w0.y + r1.y * w0.z + r1.z * w0.w;
            m += r1.w * w1.x + r2.x * w1.y + r2.y * w1.z + r2.z * w1.w;
            m += r2.w * w2.x + r3.x * w2.y + r3.y * w2.z + r3.z * w2.w;
            m += r3.w * w3.x + rv.x * w3.y + rv.y * w3.z + rv.z * w3.w;
            acc[f] = fmaxf(acc[f], m);
        }
    }
    bool any = end > start;
    int gx = (int)floorf(me.x * (1.0f/16.0f));
    int gy = (int)floorf(me.y * (1.0f/16.0f));
    int c = min(max(gx + gy * 8, 0), 63);
#pragma unroll
    for (int f = 0; f < 32; ++f) {
        float v = any ? acc[f] : 0.0f;
        float y = fmaxf(v * scale[f] + shift[f], 0.0f);
        atomicMax(&lpool[c * 32 + f], enc(y));
    }
    __syncthreads();
    // flush: skip atomics that cannot improve (stale reads are <= current: safe)
    for (int i = threadIdx.x; i < 2048; i += 256) {
        unsigned u = lpool[i];
        if (u > pool[i]) atomicMax(&pool[i], u);
    }
}

__global__ __launch_bounds__(256) void pool_decode(const unsigned* __restrict__ pool,
                                                   float* __restrict__ out) {
    int i = blockIdx.x * 256 + threadIdx.x;   // 2048
    unsigned u = pool[i];
    out[i] = (u == 0u) ? 0.0f : dec(u);
}

extern "C" void kernel_launch(void* const* d_in, const int* in_sizes, int n_in,
                              void* d_out, int out_size, void* d_ws, size_t ws_size,
                              hipStream_t stream) {
    const float* x    = (const float*)d_in[0];
    const float* pos  = (const float*)d_in[1];
    const int*   ei   = (const int*)d_in[2];
    const float* W1   = (const float*)d_in[3];
    const float* b1   = (const float*)d_in[4];
    const float* bn1m = (const float*)d_in[5];
    const float* bn1v = (const float*)d_in[6];
    const float* bn1w = (const float*)d_in[7];
    const float* bn1b = (const float*)d_in[8];
    const float* W2   = (const float*)d_in[9];
    const float* b2   = (const float*)d_in[10];
    const float* bn2m = (const float*)d_in[11];
    const float* bn2v = (const float*)d_in[12];
    const float* bn2w = (const float*)d_in[13];
    const float* bn2b = (const float*)d_in[14];

    int* deg       = (int*)d_ws;                        // N    [zeroed]
    unsigned* pool = (unsigned*)(deg + N_NODES);        // 2048 [zeroed]
    int* dhist     = (int*)(pool + 2048);               // 64   [zeroed]
    int* dcur      = dhist + 64;                        // 64
    int* offs      = dcur + 64;                         // N
    int* cursor    = offs + N_NODES;                    // N
    int* csr_src   = cursor + N_NODES;                  // E = 8N
    float* px4     = (float*)(csr_src + N_EDGES);       // 4N
    float* rec     = px4 + (size_t)N_NODES * 4;         // 32N
    int* order     = (int*)(rec + (size_t)N_NODES * 32);// N
    int* bsum      = order + N_NODES;                   // 1024
    int* boff      = bsum + 1024;                       // 1024

    hipMemsetAsync(d_ws, 0, (size_t)(N_NODES + 2048 + 64) * 4, stream);

    hist_k         <<<N_EDGES/256, 256, 0, stream>>>(ei, deg);
    pack_px        <<<N_NODES/256, 256, 0, stream>>>(pos, x, (float4*)px4);
    dhist_k        <<<N_NODES/256, 256, 0, stream>>>(deg, dhist);
    dscan_k        <<<1, 64, 0, stream>>>(dhist, dcur);
    dscatter_k     <<<N_NODES/256, 256, 0, stream>>>(deg, dcur, order);
    scan_block_sums<<<N_NODES/256, 256, 0, stream>>>(deg, bsum);
    scan_top       <<<1, 1024, 0, stream>>>(bsum, boff);
    scan_final     <<<N_NODES/256, 256, 0, stream>>>(deg, boff, offs, cursor);
    scatter_k      <<<N_EDGES/256, 256, 0, stream>>>(ei, cursor, csr_src);
    conv1_csr      <<<N_NODES/256, 256, 0, stream>>>((const float4*)px4, offs, cursor, csr_src,
                                                     order, W1, b1, bn1m, bn1v, bn1w, bn1b, rec);
    conv2_csr_pool <<<N_NODES/256, 256, 0, stream>>>(rec, offs, cursor, csr_src, order,
                                                     W2, b2, bn2m, bn2v, bn2w, bn2b, pool);
    pool_decode    <<<8, 256, 0, stream>>>(pool, (float*)d_out);
}

// Round 5
// 968.352 us; speedup vs baseline: 2.0120x; 1.6605x over previous
//
#include <hip/hip_runtime.h>

#define N_NODES 262144
#define N_EDGES 2097152
#define EPS_BN 1e-5f

// Monotone float<->uint encoding: preserves order, 0 is a sentinel below everything.
__device__ __forceinline__ unsigned enc(float f) {
    unsigned u = __float_as_uint(f);
    return (u & 0x80000000u) ? ~u : (u | 0x80000000u);
}
__device__ __forceinline__ float dec(unsigned u) {
    unsigned b = (u & 0x80000000u) ? (u & 0x7FFFFFFFu) : ~u;
    return __uint_as_float(b);
}

// ---- CSR build ----

__global__ __launch_bounds__(256) void hist_k(const int* __restrict__ ei,
                                              int* __restrict__ deg) {
    int e = blockIdx.x * 256 + threadIdx.x;
    int d = ei[N_EDGES + e];
    atomicAdd(&deg[d], 1);
}

__global__ __launch_bounds__(256) void scan_block_sums(const int* __restrict__ deg,
                                                       int* __restrict__ bsum) {
    __shared__ int s[256];
    int t = threadIdx.x;
    s[t] = deg[blockIdx.x * 256 + t];
    __syncthreads();
    for (int off = 128; off > 0; off >>= 1) {
        if (t < off) s[t] += s[t + off];
        __syncthreads();
    }
    if (t == 0) bsum[blockIdx.x] = s[0];
}

__global__ __launch_bounds__(1024) void scan_top(const int* __restrict__ bsum,
                                                 int* __restrict__ boff) {
    __shared__ int s[1024];
    int t = threadIdx.x;
    int orig = bsum[t];
    s[t] = orig;
    __syncthreads();
    for (int off = 1; off < 1024; off <<= 1) {
        int v = (t >= off) ? s[t - off] : 0;
        __syncthreads();
        s[t] += v;
        __syncthreads();
    }
    boff[t] = s[t] - orig;   // exclusive
}

__global__ __launch_bounds__(256) void scan_final(const int* __restrict__ deg,
                                                  const int* __restrict__ boff,
                                                  int* __restrict__ offs,
                                                  int* __restrict__ cursor) {
    __shared__ int s[256];
    int t = threadIdx.x;
    int i = blockIdx.x * 256 + t;
    int v = deg[i];
    s[t] = v;
    __syncthreads();
    for (int off = 1; off < 256; off <<= 1) {
        int a = (t >= off) ? s[t - off] : 0;
        __syncthreads();
        s[t] += a;
        __syncthreads();
    }
    int ex = boff[blockIdx.x] + s[t] - v;
    offs[i] = ex;
    cursor[i] = ex;
}

__global__ __launch_bounds__(256) void scatter_k(const int* __restrict__ ei,
                                                 int* __restrict__ cursor,
                                                 int* __restrict__ csr_src) {
    int e = blockIdx.x * 256 + threadIdx.x;
    int s = ei[e];
    int d = ei[N_EDGES + e];
    int p = atomicAdd(&cursor[d], 1);
    csr_src[p] = s;
}

// ---- degree sort (counting sort into 64 bins) ----

__global__ __launch_bounds__(256) void dhist_k(const int* __restrict__ deg,
                                               int* __restrict__ dhist) {
    __shared__ int hh[64];
    if (threadIdx.x < 64) hh[threadIdx.x] = 0;
    __syncthreads();
    int i = blockIdx.x * 256 + threadIdx.x;
    int b = min(deg[i], 63);
    atomicAdd(&hh[b], 1);
    __syncthreads();
    if (threadIdx.x < 64 && hh[threadIdx.x])
        atomicAdd(&dhist[threadIdx.x], hh[threadIdx.x]);
}

__global__ __launch_bounds__(64) void dscan_k(const int* __restrict__ dhist,
                                              int* __restrict__ dcur) {
    __shared__ int s[64];
    int t = threadIdx.x;
    int v = dhist[t];
    s[t] = v;
    __syncthreads();
    for (int off = 1; off < 64; off <<= 1) {
        int a = (t >= off) ? s[t - off] : 0;
        __syncthreads();
        s[t] += a;
        __syncthreads();
    }
    dcur[t] = s[t] - v;   // exclusive
}

__global__ __launch_bounds__(256) void dscatter_k(const int* __restrict__ deg,
                                                  int* __restrict__ dcur,
                                                  int* __restrict__ order) {
    __shared__ int cnt[64], base[64];
    if (threadIdx.x < 64) cnt[threadIdx.x] = 0;
    __syncthreads();
    int i = blockIdx.x * 256 + threadIdx.x;
    int b = min(deg[i], 63);
    int lr = atomicAdd(&cnt[b], 1);
    __syncthreads();
    if (threadIdx.x < 64 && cnt[threadIdx.x])
        base[threadIdx.x] = atomicAdd(&dcur[threadIdx.x], cnt[threadIdx.x]);
    __syncthreads();
    order[base[b] + lr] = i;
}

// pack [pos3, x] per node into one float4 for conv1's single-line gather
__global__ __launch_bounds__(256) void pack_px(const float* __restrict__ pos,
                                               const float* __restrict__ x,
                                               float4* __restrict__ px4) {
    int i = blockIdx.x * 256 + threadIdx.x;
    px4[i] = make_float4(pos[3*i], pos[3*i+1], pos[3*i+2], x[i]);
}

// ---- conv1: per-dst max (1+3 -> 16), fused BN+ReLU. rec[d] = [pos3, h1[16], pad] ----
__global__ __launch_bounds__(256) void conv1_csr(
    const float4* __restrict__ px4,
    const int* __restrict__ offs, const int* __restrict__ cursor,
    const int* __restrict__ csr_src, const int* __restrict__ order,
    const float* __restrict__ W1, const float* __restrict__ b1,
    const float* __restrict__ mean, const float* __restrict__ var,
    const float* __restrict__ gamma, const float* __restrict__ beta,
    float* __restrict__ rec)
{
    // w1T row f (8 floats): [w_x, w_rx, w_ry, w_rz, bias, pad, pad, pad]
    __shared__ float w1T[128], scale[16], shift[16];
    if (threadIdx.x < 128) {
        int f = threadIdx.x >> 3, k = threadIdx.x & 7;
        float v = 0.0f;
        if (k < 4) v = W1[k * 16 + f];
        else if (k == 4) v = b1[f];
        w1T[threadIdx.x] = v;
    }
    if (threadIdx.x < 16) {
        float sc = gamma[threadIdx.x] * rsqrtf(var[threadIdx.x] + EPS_BN);
        scale[threadIdx.x] = sc;
        shift[threadIdx.x] = beta[threadIdx.x] - mean[threadIdx.x] * sc;
    }
    __syncthreads();
    int d = order[blockIdx.x * 256 + threadIdx.x];
    int start = offs[d], end = cursor[d];
    float4 me = px4[d];
    float acc[16];
#pragma unroll
    for (int f = 0; f < 16; ++f) acc[f] = -INFINITY;
    for (int j = start; j < end; ++j) {
        int s = csr_src[j];
        float4 p = px4[s];
        float xs = p.w;
        float rx = p.x - me.x, ry = p.y - me.y, rz = p.z - me.z;
#pragma unroll
        for (int f = 0; f < 16; ++f) {
            const float4 wa = *(const float4*)&w1T[f * 8];
            float bias = w1T[f * 8 + 4];
            float m = bias + xs * wa.x + rx * wa.y + ry * wa.z + rz * wa.w;
            acc[f] = fmaxf(acc[f], m);
        }
    }
    bool any = end > start;
    float y[16];
#pragma unroll
    for (int f = 0; f < 16; ++f) {
        float v = any ? acc[f] : 0.0f;
        y[f] = fmaxf(v * scale[f] + shift[f], 0.0f);
    }
    float4* r4 = (float4*)(rec + (size_t)d * 32);
    r4[0] = make_float4(me.x, me.y, me.z, y[0]);
    r4[1] = make_float4(y[1], y[2], y[3], y[4]);
    r4[2] = make_float4(y[5], y[6], y[7], y[8]);
    r4[3] = make_float4(y[9], y[10], y[11], y[12]);
    r4[4] = make_float4(y[13], y[14], y[15], 0.0f);
}

// ---- conv2 + pool: lane-per-(node,channel). Wave = 2 nodes x 32 channels. ----
// 512 blocks x 4 waves x 64 iters x 2 nodes = 262144 nodes.
#define C2_BLOCKS 512
#define C2_ITERS  64
__global__ __launch_bounds__(256) void conv2_lane_pool(
    const float* __restrict__ rec, const float4* __restrict__ px4,
    const int* __restrict__ offs, const int* __restrict__ cursor,
    const int* __restrict__ csr_src, const int* __restrict__ order,
    const float* __restrict__ W2, const float* __restrict__ b2,
    const float* __restrict__ mean, const float* __restrict__ var,
    const float* __restrict__ gamma, const float* __restrict__ beta,
    unsigned* __restrict__ pool)
{
    __shared__ unsigned lpool[2048];
    for (int i = threadIdx.x; i < 2048; i += 256) lpool[i] = 0u;
    __syncthreads();

    const int wave = threadIdx.x >> 6;
    const int lane = threadIdx.x & 63;
    const int half = lane >> 5;          // which node of the pair
    const int ch   = lane & 31;          // my output channel

    // per-lane weight column: W2[k][ch] k=0..18, bias, BN scale/shift (coalesced loads)
    float wh0  = W2[ 0*32+ch], wh1  = W2[ 1*32+ch], wh2  = W2[ 2*32+ch], wh3  = W2[ 3*32+ch];
    float wh4  = W2[ 4*32+ch], wh5  = W2[ 5*32+ch], wh6  = W2[ 6*32+ch], wh7  = W2[ 7*32+ch];
    float wh8  = W2[ 8*32+ch], wh9  = W2[ 9*32+ch], wh10 = W2[10*32+ch], wh11 = W2[11*32+ch];
    float wh12 = W2[12*32+ch], wh13 = W2[13*32+ch], wh14 = W2[14*32+ch], wh15 = W2[15*32+ch];
    float wrx = W2[16*32+ch], wry = W2[17*32+ch], wrz = W2[18*32+ch];
    float bias = b2[ch];
    float sc = gamma[ch] * rsqrtf(var[ch] + EPS_BN);
    float sh = beta[ch] - mean[ch] * sc;

    int pairBase = blockIdx.x * (C2_ITERS * 4);
    for (int it = 0; it < C2_ITERS; ++it) {
        int p = pairBase + it * 4 + wave;
        int d = order[2 * p + half];          // uniform within half-wave
        int start = offs[d], end = cursor[d];
        float4 me = px4[d];
        float acc = -INFINITY;
        for (int j = start; j < end; ++j) {
            int s = csr_src[j];
            const float4* r = (const float4*)(rec + (size_t)s * 32);
            float4 r0 = r[0], r1 = r[1], r2 = r[2], r3 = r[3], rv = r[4];
            float rx = r0.x - me.x, ry = r0.y - me.y, rz = r0.z - me.z;
            // two partial chains for ILP
            float a = bias + rx * wrx;
            float b = ry * wry + rz * wrz;
            a += r0.w * wh0;  b += r1.x * wh1;
            a += r1.y * wh2;  b += r1.z * wh3;
            a += r1.w * wh4;  b += r2.x * wh5;
            a += r2.y * wh6;  b += r2.z * wh7;
            a += r2.w * wh8;  b += r3.x * wh9;
            a += r3.y * wh10; b += r3.z * wh11;
            a += r3.w * wh12; b += rv.x * wh13;
            a += rv.y * wh14; b += rv.z * wh15;
            acc = fmaxf(acc, a + b);
        }
        float v = (end > start) ? acc : 0.0f;
        float y = fmaxf(v * sc + sh, 0.0f);
        int gx = (int)floorf(me.x * (1.0f/16.0f));
        int gy = (int)floorf(me.y * (1.0f/16.0f));
        int c = min(max(gx + gy * 8, 0), 63);
        atomicMax(&lpool[c * 32 + ch], enc(y));
    }
    __syncthreads();
    // flush: skip atomics that cannot improve (stale reads are <= current: safe)
    for (int i = threadIdx.x; i < 2048; i += 256) {
        unsigned u = lpool[i];
        if (u > pool[i]) atomicMax(&pool[i], u);
    }
}

__global__ __launch_bounds__(256) void pool_decode(const unsigned* __restrict__ pool,
                                                   float* __restrict__ out) {
    int i = blockIdx.x * 256 + threadIdx.x;   // 2048
    unsigned u = pool[i];
    out[i] = (u == 0u) ? 0.0f : dec(u);
}

extern "C" void kernel_launch(void* const* d_in, const int* in_sizes, int n_in,
                              void* d_out, int out_size, void* d_ws, size_t ws_size,
                              hipStream_t stream) {
    const float* x    = (const float*)d_in[0];
    const float* pos  = (const float*)d_in[1];
    const int*   ei   = (const int*)d_in[2];
    const float* W1   = (const float*)d_in[3];
    const float* b1   = (const float*)d_in[4];
    const float* bn1m = (const float*)d_in[5];
    const float* bn1v = (const float*)d_in[6];
    const float* bn1w = (const float*)d_in[7];
    const float* bn1b = (const float*)d_in[8];
    const float* W2   = (const float*)d_in[9];
    const float* b2   = (const float*)d_in[10];
    const float* bn2m = (const float*)d_in[11];
    const float* bn2v = (const float*)d_in[12];
    const float* bn2w = (const float*)d_in[13];
    const float* bn2b = (const float*)d_in[14];

    int* deg       = (int*)d_ws;                        // N    [zeroed]
    unsigned* pool = (unsigned*)(deg + N_NODES);        // 2048 [zeroed]
    int* dhist     = (int*)(pool + 2048);               // 64   [zeroed]
    int* dcur      = dhist + 64;                        // 64
    int* offs      = dcur + 64;                         // N
    int* cursor    = offs + N_NODES;                    // N
    int* csr_src   = cursor + N_NODES;                  // E = 8N
    float* px4     = (float*)(csr_src + N_EDGES);       // 4N
    float* rec     = px4 + (size_t)N_NODES * 4;         // 32N
    int* order     = (int*)(rec + (size_t)N_NODES * 32);// N
    int* bsum      = order + N_NODES;                   // 1024
    int* boff      = bsum + 1024;                       // 1024

    hipMemsetAsync(d_ws, 0, (size_t)(N_NODES + 2048 + 64) * 4, stream);

    hist_k         <<<N_EDGES/256, 256, 0, stream>>>(ei, deg);
    pack_px        <<<N_NODES/256, 256, 0, stream>>>(pos, x, (float4*)px4);
    dhist_k        <<<N_NODES/256, 256, 0, stream>>>(deg, dhist);
    dscan_k        <<<1, 64, 0, stream>>>(dhist, dcur);
    dscatter_k     <<<N_NODES/256, 256, 0, stream>>>(deg, dcur, order);
    scan_block_sums<<<N_NODES/256, 256, 0, stream>>>(deg, bsum);
    scan_top       <<<1, 1024, 0, stream>>>(bsum, boff);
    scan_final     <<<N_NODES/256, 256, 0, stream>>>(deg, boff, offs, cursor);
    scatter_k      <<<N_EDGES/256, 256, 0, stream>>>(ei, cursor, csr_src);
    conv1_csr      <<<N_NODES/256, 256, 0, stream>>>((const float4*)px4, offs, cursor, csr_src,
                                                     order, W1, b1, bn1m, bn1v, bn1w, bn1b, rec);
    conv2_lane_pool<<<C2_BLOCKS, 256, 0, stream>>>(rec, (const float4*)px4, offs, cursor,
                                                   csr_src, order,
                                                   W2, b2, bn2m, bn2v, bn2w, bn2b, pool);
    pool_decode    <<<8, 256, 0, stream>>>(pool, (float*)d_out);
}

// Round 6
// 740.502 us; speedup vs baseline: 2.6311x; 1.3077x over previous
//
#include <hip/hip_runtime.h>

#define N_NODES 262144
#define N_EDGES 2097152
#define EPS_BN 1e-5f

// Monotone float<->uint encoding: preserves order, 0 is a sentinel below everything.
__device__ __forceinline__ unsigned enc(float f) {
    unsigned u = __float_as_uint(f);
    return (u & 0x80000000u) ? ~u : (u | 0x80000000u);
}
__device__ __forceinline__ float dec(unsigned u) {
    unsigned b = (u & 0x80000000u) ? (u & 0x7FFFFFFFu) : ~u;
    return __uint_as_float(b);
}

// ---- CSR build ----

__global__ __launch_bounds__(256) void hist_k(const int* __restrict__ ei,
                                              int* __restrict__ deg) {
    int e = blockIdx.x * 256 + threadIdx.x;
    int d = ei[N_EDGES + e];
    atomicAdd(&deg[d], 1);
}

// fused: per-block degree sum (for CSR scan) + degree histogram (for sort)
__global__ __launch_bounds__(256) void scan_block_sums(const int* __restrict__ deg,
                                                       int* __restrict__ bsum,
                                                       int* __restrict__ dhist) {
    __shared__ int s[256];
    __shared__ int hh[64];
    int t = threadIdx.x;
    if (t < 64) hh[t] = 0;
    int v = deg[blockIdx.x * 256 + t];
    s[t] = v;
    __syncthreads();
    atomicAdd(&hh[min(v, 63)], 1);
    for (int off = 128; off > 0; off >>= 1) {
        if (t < off) s[t] += s[t + off];
        __syncthreads();
    }
    if (t == 0) bsum[blockIdx.x] = s[0];
    if (t < 64 && hh[t]) atomicAdd(&dhist[t], hh[t]);
}

__global__ __launch_bounds__(1024) void scan_top(const int* __restrict__ bsum,
                                                 int* __restrict__ boff) {
    __shared__ int s[1024];
    int t = threadIdx.x;
    int orig = bsum[t];
    s[t] = orig;
    __syncthreads();
    for (int off = 1; off < 1024; off <<= 1) {
        int v = (t >= off) ? s[t - off] : 0;
        __syncthreads();
        s[t] += v;
        __syncthreads();
    }
    boff[t] = s[t] - orig;   // exclusive
}

__global__ __launch_bounds__(256) void scan_final(const int* __restrict__ deg,
                                                  const int* __restrict__ boff,
                                                  int* __restrict__ offs,
                                                  int* __restrict__ cursor) {
    __shared__ int s[256];
    int t = threadIdx.x;
    int i = blockIdx.x * 256 + t;
    int v = deg[i];
    s[t] = v;
    __syncthreads();
    for (int off = 1; off < 256; off <<= 1) {
        int a = (t >= off) ? s[t - off] : 0;
        __syncthreads();
        s[t] += a;
        __syncthreads();
    }
    int ex = boff[blockIdx.x] + s[t] - v;
    offs[i] = ex;
    cursor[i] = ex;
}

__global__ __launch_bounds__(256) void scatter_k(const int* __restrict__ ei,
                                                 int* __restrict__ cursor,
                                                 int* __restrict__ csr_src) {
    int e = blockIdx.x * 256 + threadIdx.x;
    int s = ei[e];
    int d = ei[N_EDGES + e];
    int p = atomicAdd(&cursor[d], 1);
    csr_src[p] = s;
}

// ---- degree sort (counting sort into 64 bins) ----

__global__ __launch_bounds__(64) void dscan_k(const int* __restrict__ dhist,
                                              int* __restrict__ dcur) {
    __shared__ int s[64];
    int t = threadIdx.x;
    int v = dhist[t];
    s[t] = v;
    __syncthreads();
    for (int off = 1; off < 64; off <<= 1) {
        int a = (t >= off) ? s[t - off] : 0;
        __syncthreads();
        s[t] += a;
        __syncthreads();
    }
    dcur[t] = s[t] - v;   // exclusive
}

__global__ __launch_bounds__(256) void dscatter_k(const int* __restrict__ deg,
                                                  int* __restrict__ dcur,
                                                  int* __restrict__ order) {
    __shared__ int cnt[64], base[64];
    if (threadIdx.x < 64) cnt[threadIdx.x] = 0;
    __syncthreads();
    int i = blockIdx.x * 256 + threadIdx.x;
    int b = min(deg[i], 63);
    int lr = atomicAdd(&cnt[b], 1);
    __syncthreads();
    if (threadIdx.x < 64 && cnt[threadIdx.x])
        base[threadIdx.x] = atomicAdd(&dcur[threadIdx.x], cnt[threadIdx.x]);
    __syncthreads();
    order[base[b] + lr] = i;
}

// pack [pos3, x] per node into one float4 for conv1's single-line gather
__global__ __launch_bounds__(256) void pack_px(const float* __restrict__ pos,
                                               const float* __restrict__ x,
                                               float4* __restrict__ px4) {
    int i = blockIdx.x * 256 + threadIdx.x;
    px4[i] = make_float4(pos[3*i], pos[3*i+1], pos[3*i+2], x[i]);
}

// ---- conv1: per-dst max (1+3 -> 16), fused BN+ReLU. rec[d] = [pos3, h1[16], pad] ----
__global__ __launch_bounds__(256) void conv1_csr(
    const float4* __restrict__ px4,
    const int* __restrict__ offs, const int* __restrict__ cursor,
    const int* __restrict__ csr_src, const int* __restrict__ order,
    const float* __restrict__ W1, const float* __restrict__ b1,
    const float* __restrict__ mean, const float* __restrict__ var,
    const float* __restrict__ gamma, const float* __restrict__ beta,
    float* __restrict__ rec)
{
    // w1T row f (8 floats): [w_x, w_rx, w_ry, w_rz, bias, pad, pad, pad]
    __shared__ float w1T[128], scale[16], shift[16];
    if (threadIdx.x < 128) {
        int f = threadIdx.x >> 3, k = threadIdx.x & 7;
        float v = 0.0f;
        if (k < 4) v = W1[k * 16 + f];
        else if (k == 4) v = b1[f];
        w1T[threadIdx.x] = v;
    }
    if (threadIdx.x < 16) {
        float sc = gamma[threadIdx.x] * rsqrtf(var[threadIdx.x] + EPS_BN);
        scale[threadIdx.x] = sc;
        shift[threadIdx.x] = beta[threadIdx.x] - mean[threadIdx.x] * sc;
    }
    __syncthreads();
    int d = order[blockIdx.x * 256 + threadIdx.x];
    int start = offs[d], end = cursor[d];
    float4 me = px4[d];
    float acc[16];
#pragma unroll
    for (int f = 0; f < 16; ++f) acc[f] = -INFINITY;
    for (int j = start; j < end; ++j) {
        int s = csr_src[j];
        float4 p = px4[s];
        float xs = p.w;
        float rx = p.x - me.x, ry = p.y - me.y, rz = p.z - me.z;
#pragma unroll
        for (int f = 0; f < 16; ++f) {
            const float4 wa = *(const float4*)&w1T[f * 8];
            float bias = w1T[f * 8 + 4];
            float m = bias + xs * wa.x + rx * wa.y + ry * wa.z + rz * wa.w;
            acc[f] = fmaxf(acc[f], m);
        }
    }
    bool any = end > start;
    float y[16];
#pragma unroll
    for (int f = 0; f < 16; ++f) {
        float v = any ? acc[f] : 0.0f;
        y[f] = fmaxf(v * scale[f] + shift[f], 0.0f);
    }
    float4* r4 = (float4*)(rec + (size_t)d * 32);
    r4[0] = make_float4(me.x, me.y, me.z, y[0]);
    r4[1] = make_float4(y[1], y[2], y[3], y[4]);
    r4[2] = make_float4(y[5], y[6], y[7], y[8]);
    r4[3] = make_float4(y[9], y[10], y[11], y[12]);
    r4[4] = make_float4(y[13], y[14], y[15], 0.0f);
}

// ---- conv2 + pool: lane-per-(node,channel). Wave = 2 nodes x 32 channels. ----
// 2048 blocks x 4 waves x 16 iters x 2 nodes = 262144 nodes.
#define C2_BLOCKS 2048
#define C2_ITERS  16

__device__ __forceinline__ float c2_msg(
    const float* __restrict__ rec, int s, float4 me,
    float wh0, float wh1, float wh2, float wh3, float wh4, float wh5,
    float wh6, float wh7, float wh8, float wh9, float wh10, float wh11,
    float wh12, float wh13, float wh14, float wh15,
    float wrx, float wry, float wrz, float bias)
{
    const float4* r = (const float4*)(rec + (size_t)s * 32);
    float4 r0 = r[0], r1 = r[1], r2 = r[2], r3 = r[3], rv = r[4];
    float rx = r0.x - me.x, ry = r0.y - me.y, rz = r0.z - me.z;
    float a = bias + rx * wrx;
    float b = ry * wry + rz * wrz;
    a += r0.w * wh0;  b += r1.x * wh1;
    a += r1.y * wh2;  b += r1.z * wh3;
    a += r1.w * wh4;  b += r2.x * wh5;
    a += r2.y * wh6;  b += r2.z * wh7;
    a += r2.w * wh8;  b += r3.x * wh9;
    a += r3.y * wh10; b += r3.z * wh11;
    a += r3.w * wh12; b += rv.x * wh13;
    a += rv.y * wh14; b += rv.z * wh15;
    return a + b;
}

__global__ __launch_bounds__(256) void conv2_lane_pool(
    const float* __restrict__ rec, const float4* __restrict__ px4,
    const int* __restrict__ offs, const int* __restrict__ cursor,
    const int* __restrict__ csr_src, const int* __restrict__ order,
    const float* __restrict__ W2, const float* __restrict__ b2,
    const float* __restrict__ mean, const float* __restrict__ var,
    const float* __restrict__ gamma, const float* __restrict__ beta,
    unsigned* __restrict__ pool)
{
    __shared__ unsigned lpool[2048];
    for (int i = threadIdx.x; i < 2048; i += 256) lpool[i] = 0u;
    __syncthreads();

    const int wave = threadIdx.x >> 6;
    const int lane = threadIdx.x & 63;
    const int half = lane >> 5;          // which node of the pair
    const int ch   = lane & 31;          // my output channel

    // per-lane weight column: W2[k][ch] k=0..18, bias, BN scale/shift (coalesced loads)
    float wh0  = W2[ 0*32+ch], wh1  = W2[ 1*32+ch], wh2  = W2[ 2*32+ch], wh3  = W2[ 3*32+ch];
    float wh4  = W2[ 4*32+ch], wh5  = W2[ 5*32+ch], wh6  = W2[ 6*32+ch], wh7  = W2[ 7*32+ch];
    float wh8  = W2[ 8*32+ch], wh9  = W2[ 9*32+ch], wh10 = W2[10*32+ch], wh11 = W2[11*32+ch];
    float wh12 = W2[12*32+ch], wh13 = W2[13*32+ch], wh14 = W2[14*32+ch], wh15 = W2[15*32+ch];
    float wrx = W2[16*32+ch], wry = W2[17*32+ch], wrz = W2[18*32+ch];
    float bias = b2[ch];
    float sc = gamma[ch] * rsqrtf(var[ch] + EPS_BN);
    float sh = beta[ch] - mean[ch] * sc;

    int pairBase = blockIdx.x * (C2_ITERS * 4);
    for (int it = 0; it < C2_ITERS; ++it) {
        int p = pairBase + it * 4 + wave;
        int d = order[2 * p + half];          // uniform within half-wave
        int start = offs[d], end = cursor[d];
        float4 me = px4[d];
        float acc = -INFINITY;
        int j = start;
        // unroll x2: two independent gather+compute chains in flight
        for (; j + 2 <= end; j += 2) {
            int s0 = csr_src[j], s1 = csr_src[j + 1];
            float m0 = c2_msg(rec, s0, me, wh0,wh1,wh2,wh3,wh4,wh5,wh6,wh7,
                              wh8,wh9,wh10,wh11,wh12,wh13,wh14,wh15, wrx,wry,wrz,bias);
            float m1 = c2_msg(rec, s1, me, wh0,wh1,wh2,wh3,wh4,wh5,wh6,wh7,
                              wh8,wh9,wh10,wh11,wh12,wh13,wh14,wh15, wrx,wry,wrz,bias);
            acc = fmaxf(acc, fmaxf(m0, m1));
        }
        if (j < end) {
            int s0 = csr_src[j];
            float m0 = c2_msg(rec, s0, me, wh0,wh1,wh2,wh3,wh4,wh5,wh6,wh7,
                              wh8,wh9,wh10,wh11,wh12,wh13,wh14,wh15, wrx,wry,wrz,bias);
            acc = fmaxf(acc, m0);
        }
        float v = (end > start) ? acc : 0.0f;
        float y = fmaxf(v * sc + sh, 0.0f);
        int gx = (int)floorf(me.x * (1.0f/16.0f));
        int gy = (int)floorf(me.y * (1.0f/16.0f));
        int c = min(max(gx + gy * 8, 0), 63);
        atomicMax(&lpool[c * 32 + ch], enc(y));
    }
    __syncthreads();
    // flush: skip atomics that cannot improve (stale reads are <= current: safe)
    for (int i = threadIdx.x; i < 2048; i += 256) {
        unsigned u = lpool[i];
        if (u > pool[i]) atomicMax(&pool[i], u);
    }
}

__global__ __launch_bounds__(256) void pool_decode(const unsigned* __restrict__ pool,
                                                   float* __restrict__ out) {
    int i = blockIdx.x * 256 + threadIdx.x;   // 2048
    unsigned u = pool[i];
    out[i] = (u == 0u) ? 0.0f : dec(u);
}

extern "C" void kernel_launch(void* const* d_in, const int* in_sizes, int n_in,
                              void* d_out, int out_size, void* d_ws, size_t ws_size,
                              hipStream_t stream) {
    const float* x    = (const float*)d_in[0];
    const float* pos  = (const float*)d_in[1];
    const int*   ei   = (const int*)d_in[2];
    const float* W1   = (const float*)d_in[3];
    const float* b1   = (const float*)d_in[4];
    const float* bn1m = (const float*)d_in[5];
    const float* bn1v = (const float*)d_in[6];
    const float* bn1w = (const float*)d_in[7];
    const float* bn1b = (const float*)d_in[8];
    const float* W2   = (const float*)d_in[9];
    const float* b2   = (const float*)d_in[10];
    const float* bn2m = (const float*)d_in[11];
    const float* bn2v = (const float*)d_in[12];
    const float* bn2w = (const float*)d_in[13];
    const float* bn2b = (const float*)d_in[14];

    int* deg       = (int*)d_ws;                        // N    [zeroed]
    unsigned* pool = (unsigned*)(deg + N_NODES);        // 2048 [zeroed]
    int* dhist     = (int*)(pool + 2048);               // 64   [zeroed]
    int* dcur      = dhist + 64;                        // 64
    int* offs      = dcur + 64;                         // N
    int* cursor    = offs + N_NODES;                    // N
    int* csr_src   = cursor + N_NODES;                  // E = 8N
    float* px4     = (float*)(csr_src + N_EDGES);       // 4N
    float* rec     = px4 + (size_t)N_NODES * 4;         // 32N
    int* order     = (int*)(rec + (size_t)N_NODES * 32);// N
    int* bsum      = order + N_NODES;                   // 1024
    int* boff      = bsum + 1024;                       // 1024

    hipMemsetAsync(d_ws, 0, (size_t)(N_NODES + 2048 + 64) * 4, stream);

    hist_k         <<<N_EDGES/256, 256, 0, stream>>>(ei, deg);
    pack_px        <<<N_NODES/256, 256, 0, stream>>>(pos, x, (float4*)px4);
    scan_block_sums<<<N_NODES/256, 256, 0, stream>>>(deg, bsum, dhist);
    dscan_k        <<<1, 64, 0, stream>>>(dhist, dcur);
    dscatter_k     <<<N_NODES/256, 256, 0, stream>>>(deg, dcur, order);
    scan_top       <<<1, 1024, 0, stream>>>(bsum, boff);
    scan_final     <<<N_NODES/256, 256, 0, stream>>>(deg, boff, offs, cursor);
    scatter_k      <<<N_EDGES/256, 256, 0, stream>>>(ei, cursor, csr_src);
    conv1_csr      <<<N_NODES/256, 256, 0, stream>>>((const float4*)px4, offs, cursor, csr_src,
                                                     order, W1, b1, bn1m, bn1v, bn1w, bn1b, rec);
    conv2_lane_pool<<<C2_BLOCKS, 256, 0, stream>>>(rec, (const float4*)px4, offs, cursor,
                                                   csr_src, order,
                                                   W2, b2, bn2m, bn2v, bn2w, bn2b, pool);
    pool_decode    <<<8, 256, 0, stream>>>(pool, (float*)d_out);
}

// Round 7
// 541.761 us; speedup vs baseline: 3.5963x; 1.3668x over previous
//
#include <hip/hip_runtime.h>
#include <hip/hip_fp16.h>

#define N_NODES 262144
#define N_EDGES 2097152
#define EPS_BN 1e-5f

// Monotone float<->uint encoding: preserves order, 0 is a sentinel below everything.
__device__ __forceinline__ unsigned enc(float f) {
    unsigned u = __float_as_uint(f);
    return (u & 0x80000000u) ? ~u : (u | 0x80000000u);
}
__device__ __forceinline__ float dec(unsigned u) {
    unsigned b = (u & 0x80000000u) ? (u & 0x7FFFFFFFu) : ~u;
    return __uint_as_float(b);
}

// ---- CSR build ----

__global__ __launch_bounds__(256) void hist_k(const int* __restrict__ ei,
                                              int* __restrict__ deg) {
    int e = blockIdx.x * 256 + threadIdx.x;
    int d = ei[N_EDGES + e];
    atomicAdd(&deg[d], 1);
}

__global__ __launch_bounds__(256) void scan_block_sums(const int* __restrict__ deg,
                                                       int* __restrict__ bsum) {
    __shared__ int s[256];
    int t = threadIdx.x;
    s[t] = deg[blockIdx.x * 256 + t];
    __syncthreads();
    for (int off = 128; off > 0; off >>= 1) {
        if (t < off) s[t] += s[t + off];
        __syncthreads();
    }
    if (t == 0) bsum[blockIdx.x] = s[0];
}

__global__ __launch_bounds__(1024) void scan_top(const int* __restrict__ bsum,
                                                 int* __restrict__ boff) {
    __shared__ int s[1024];
    int t = threadIdx.x;
    int orig = bsum[t];
    s[t] = orig;
    __syncthreads();
    for (int off = 1; off < 1024; off <<= 1) {
        int v = (t >= off) ? s[t - off] : 0;
        __syncthreads();
        s[t] += v;
        __syncthreads();
    }
    boff[t] = s[t] - orig;   // exclusive
}

__global__ __launch_bounds__(256) void scan_final(const int* __restrict__ deg,
                                                  const int* __restrict__ boff,
                                                  int* __restrict__ offs,
                                                  int* __restrict__ cursor) {
    __shared__ int s[256];
    int t = threadIdx.x;
    int i = blockIdx.x * 256 + t;
    int v = deg[i];
    s[t] = v;
    __syncthreads();
    for (int off = 1; off < 256; off <<= 1) {
        int a = (t >= off) ? s[t - off] : 0;
        __syncthreads();
        s[t] += a;
        __syncthreads();
    }
    int ex = boff[blockIdx.x] + s[t] - v;
    offs[i] = ex;
    cursor[i] = ex;
}

__global__ __launch_bounds__(256) void scatter_k(const int* __restrict__ ei,
                                                 int* __restrict__ cursor,
                                                 int* __restrict__ csr_src) {
    int e = blockIdx.x * 256 + threadIdx.x;
    int s = ei[e];
    int d = ei[N_EDGES + e];
    int p = atomicAdd(&cursor[d], 1);
    csr_src[p] = s;
}

// ---- alpha precompute: alpha[n][ch] = b1 + W1x*x_n + W1r . pos_n  (fp32) ----
__global__ __launch_bounds__(256) void alpha_k(const float* __restrict__ x,
                                               const float* __restrict__ pos,
                                               const float* __restrict__ W1,
                                               const float* __restrict__ b1,
                                               float* __restrict__ alpha) {
    int t = blockIdx.x * 256 + threadIdx.x;   // N*16 threads
    int n = t >> 4, ch = t & 15;
    float a = b1[ch] + W1[ch] * x[n]
            + W1[16 + ch] * pos[3*n] + W1[32 + ch] * pos[3*n+1] + W1[48 + ch] * pos[3*n+2];
    alpha[t] = a;
}

// ---- conv1 fused: gather-max alpha -> BN+ReLU -> h (in LDS) -> beta (fp16) ----
// wave = 4 nodes x 16 ch. 1024 blocks x 4 waves x 16 iters x 4 nodes = 262144.
#define C1_BLOCKS 1024
#define C1_ITERS  16
__global__ __launch_bounds__(256) void conv1_fused(
    const float* __restrict__ alpha, const float* __restrict__ pos,
    const int* __restrict__ offs, const int* __restrict__ deg,
    const int* __restrict__ csr_src,
    const float* __restrict__ W1,
    const float* __restrict__ mean, const float* __restrict__ var,
    const float* __restrict__ gamma, const float* __restrict__ beta_bn,
    const float* __restrict__ W2, const float* __restrict__ b2,
    __half* __restrict__ beta)
{
    __shared__ float w2s[608], b2s[32];
    __shared__ float hs[4][64];      // per wave: 4 nodes x 16
    __shared__ float ps[4][12];      // per wave: 4 nodes x 3
    __shared__ int   ns[4][4];
    for (int i = threadIdx.x; i < 608; i += 256) w2s[i] = W2[i];
    if (threadIdx.x < 32) b2s[threadIdx.x] = b2[threadIdx.x];

    const int wave = threadIdx.x >> 6;
    const int lane = threadIdx.x & 63;
    const int q    = lane >> 4;      // node within wave
    const int ch   = lane & 15;
    const int c    = lane & 31;      // beta-phase channel
    const int nlo  = lane >> 5;      // beta-phase node offset

    float wrx = W1[16 + ch], wry = W1[32 + ch], wrz = W1[48 + ch];
    float sc = gamma[ch] * rsqrtf(var[ch] + EPS_BN);
    float sh = beta_bn[ch] - mean[ch] * sc;
    __syncthreads();

    for (int it = 0; it < C1_ITERS; ++it) {
        int task = (it * 4 + wave) * C1_BLOCKS + blockIdx.x;
        int n = task * 4 + q;
        int start = offs[n], dg = deg[n];
        float px = pos[3*n], py = pos[3*n+1], pz = pos[3*n+2];
        float m = -INFINITY;
        int j = start, end = start + dg;
        for (; j + 2 <= end; j += 2) {
            int s0 = csr_src[j], s1 = csr_src[j+1];
            float a0 = alpha[s0 * 16 + ch];
            float a1 = alpha[s1 * 16 + ch];
            m = fmaxf(m, fmaxf(a0, a1));
        }
        if (j < end) m = fmaxf(m, alpha[csr_src[j] * 16 + ch]);
        float v = dg ? (m - (wrx*px + wry*py + wrz*pz)) : 0.0f;
        float h = fmaxf(v * sc + sh, 0.0f);
        hs[wave][q * 16 + ch] = h;
        if (ch == 0) ns[wave][q] = n;
        if (ch < 3) ps[wave][q * 3 + ch] = (ch == 0) ? px : ((ch == 1) ? py : pz);
        __syncthreads();
        // beta phase: 4 nodes x 32 ch with 64 lanes -> 2 passes
#pragma unroll
        for (int p = 0; p < 2; ++p) {
            int nl = nlo + p * 2;
            float bsv = b2s[c];
#pragma unroll
            for (int k = 0; k < 16; ++k)
                bsv += w2s[k * 32 + c] * hs[wave][nl * 16 + k];
            float qx = ps[wave][nl*3], qy = ps[wave][nl*3+1], qz = ps[wave][nl*3+2];
            bsv += w2s[16*32 + c] * qx + w2s[17*32 + c] * qy + w2s[18*32 + c] * qz;
            beta[(size_t)ns[wave][nl] * 32 + c] = __float2half(bsv);
        }
        __syncthreads();
    }
}

// ---- conv2 + pool: gather-max beta(fp16) -> BN+ReLU -> voxel pool ----
// wave = 2 nodes x 32 ch. 2048 blocks x 4 waves x 16 iters x 2 nodes = 262144.
#define C2_BLOCKS 2048
#define C2_ITERS  16
__global__ __launch_bounds__(256) void conv2_pool(
    const __half* __restrict__ beta, const float* __restrict__ pos,
    const int* __restrict__ offs, const int* __restrict__ deg,
    const int* __restrict__ csr_src,
    const float* __restrict__ W2,
    const float* __restrict__ mean, const float* __restrict__ var,
    const float* __restrict__ gamma, const float* __restrict__ beta_bn,
    unsigned* __restrict__ pool)
{
    __shared__ unsigned lpool[2048];
    for (int i = threadIdx.x; i < 2048; i += 256) lpool[i] = 0u;
    __syncthreads();

    const int wave = threadIdx.x >> 6;
    const int lane = threadIdx.x & 63;
    const int half = lane >> 5;
    const int ch   = lane & 31;

    float wrx = W2[16*32 + ch], wry = W2[17*32 + ch], wrz = W2[18*32 + ch];
    float sc = gamma[ch] * rsqrtf(var[ch] + EPS_BN);
    float sh = beta_bn[ch] - mean[ch] * sc;

    for (int it = 0; it < C2_ITERS; ++it) {
        int task = (it * 4 + wave) * C2_BLOCKS + blockIdx.x;
        int n = task * 2 + half;
        int start = offs[n], dg = deg[n];
        float px = pos[3*n], py = pos[3*n+1], pz = pos[3*n+2];
        float m = -INFINITY;
        int j = start, end = start + dg;
        for (; j + 2 <= end; j += 2) {
            int s0 = csr_src[j], s1 = csr_src[j+1];
            float b0 = __half2float(beta[(size_t)s0 * 32 + ch]);
            float b1 = __half2float(beta[(size_t)s1 * 32 + ch]);
            m = fmaxf(m, fmaxf(b0, b1));
        }
        if (j < end) m = fmaxf(m, __half2float(beta[(size_t)csr_src[j] * 32 + ch]));
        float v = dg ? (m - (wrx*px + wry*py + wrz*pz)) : 0.0f;
        float y = fmaxf(v * sc + sh, 0.0f);
        int gx = (int)floorf(px * (1.0f/16.0f));
        int gy = (int)floorf(py * (1.0f/16.0f));
        int cl = min(max(gx + gy * 8, 0), 63);
        atomicMax(&lpool[cl * 32 + ch], enc(y));
    }
    __syncthreads();
    // flush: skip atomics that cannot improve (stale reads <= current: safe)
    for (int i = threadIdx.x; i < 2048; i += 256) {
        unsigned u = lpool[i];
        if (u > pool[i]) atomicMax(&pool[i], u);
    }
}

__global__ __launch_bounds__(256) void pool_decode(const unsigned* __restrict__ pool,
                                                   float* __restrict__ out) {
    int i = blockIdx.x * 256 + threadIdx.x;   // 2048
    unsigned u = pool[i];
    out[i] = (u == 0u) ? 0.0f : dec(u);
}

extern "C" void kernel_launch(void* const* d_in, const int* in_sizes, int n_in,
                              void* d_out, int out_size, void* d_ws, size_t ws_size,
                              hipStream_t stream) {
    const float* x    = (const float*)d_in[0];
    const float* pos  = (const float*)d_in[1];
    const int*   ei   = (const int*)d_in[2];
    const float* W1   = (const float*)d_in[3];
    const float* b1   = (const float*)d_in[4];
    const float* bn1m = (const float*)d_in[5];
    const float* bn1v = (const float*)d_in[6];
    const float* bn1w = (const float*)d_in[7];
    const float* bn1b = (const float*)d_in[8];
    const float* W2   = (const float*)d_in[9];
    const float* b2   = (const float*)d_in[10];
    const float* bn2m = (const float*)d_in[11];
    const float* bn2v = (const float*)d_in[12];
    const float* bn2w = (const float*)d_in[13];
    const float* bn2b = (const float*)d_in[14];

    int* deg       = (int*)d_ws;                         // N    [zeroed]
    unsigned* pool = (unsigned*)(deg + N_NODES);         // 2048 [zeroed]
    int* offs      = (int*)(pool + 2048);                // N
    int* cursor    = offs + N_NODES;                     // N
    int* csr_src   = cursor + N_NODES;                   // 8N
    float* alpha   = (float*)(csr_src + N_EDGES);        // 16N fp32
    __half* beta   = (__half*)(alpha + (size_t)N_NODES*16); // 32N fp16 = 16N words
    int* bsum      = (int*)((float*)alpha + (size_t)N_NODES*16 + (size_t)N_NODES*16); // 1024
    int* boff      = bsum + 1024;                        // 1024

    hipMemsetAsync(d_ws, 0, (size_t)(N_NODES + 2048) * 4, stream);

    hist_k         <<<N_EDGES/256, 256, 0, stream>>>(ei, deg);
    alpha_k        <<<N_NODES*16/256, 256, 0, stream>>>(x, pos, W1, b1, alpha);
    scan_block_sums<<<N_NODES/256, 256, 0, stream>>>(deg, bsum);
    scan_top       <<<1, 1024, 0, stream>>>(bsum, boff);
    scan_final     <<<N_NODES/256, 256, 0, stream>>>(deg, boff, offs, cursor);
    scatter_k      <<<N_EDGES/256, 256, 0, stream>>>(ei, cursor, csr_src);
    conv1_fused    <<<C1_BLOCKS, 256, 0, stream>>>(alpha, pos, offs, deg, csr_src,
                                                   W1, bn1m, bn1v, bn1w, bn1b, W2, b2, beta);
    conv2_pool     <<<C2_BLOCKS, 256, 0, stream>>>(beta, pos, offs, deg, csr_src,
                                                   W2, bn2m, bn2v, bn2w, bn2b, pool);
    pool_decode    <<<8, 256, 0, stream>>>(pool, (float*)d_out);
}

// Round 8
// 362.137 us; speedup vs baseline: 5.3801x; 1.4960x over previous
//
#include <hip/hip_runtime.h>
#include <hip/hip_fp16.h>

#define N_NODES 262144
#define N_EDGES 2097152
#define EPS_BN 1e-5f

// Monotone float<->uint encoding: preserves order, 0 is a sentinel below everything.
__device__ __forceinline__ unsigned enc(float f) {
    unsigned u = __float_as_uint(f);
    return (u & 0x80000000u) ? ~u : (u | 0x80000000u);
}
__device__ __forceinline__ float dec(unsigned u) {
    unsigned b = (u & 0x80000000u) ? (u & 0x7FFFFFFFu) : ~u;
    return __uint_as_float(b);
}

// ---- CSR build: two-level bucket grouping (no global value scatter) ----
// bucket b = dst >> 10  (256 buckets x 1024 dsts; N = 256*1024 exactly)

__global__ __launch_bounds__(256) void hist_bucket(const int* __restrict__ ei,
                                                   int* __restrict__ btot) {
    __shared__ int hh[256];
    int t = threadIdx.x;
    hh[t] = 0;
    __syncthreads();
    int base = blockIdx.x * 4096;
    for (int k = 0; k < 16; ++k) {
        int d = ei[N_EDGES + base + k * 256 + t];
        atomicAdd(&hh[d >> 10], 1);
    }
    __syncthreads();
    if (hh[t]) atomicAdd(&btot[t], hh[t]);
}

__global__ __launch_bounds__(256) void scan256_k(const int* __restrict__ btot,
                                                 int* __restrict__ bbase,
                                                 int* __restrict__ bcur) {
    __shared__ int s[256];
    int t = threadIdx.x;
    int v = btot[t];
    s[t] = v;
    __syncthreads();
    for (int off = 1; off < 256; off <<= 1) {
        int a = (t >= off) ? s[t - off] : 0;
        __syncthreads();
        s[t] += a;
        __syncthreads();
    }
    bbase[t] = s[t] - v;
    bcur[t]  = s[t] - v;
    if (t == 255) bbase[256] = s[255];
}

// partition edges into coarse buckets; each block writes ~128-B runs per bucket
__global__ __launch_bounds__(256) void part_k(const int* __restrict__ ei,
                                              int* __restrict__ bcur,
                                              int2* __restrict__ pairs) {
    __shared__ int hh[256], bb[256];
    int t = threadIdx.x;
    hh[t] = 0;
    __syncthreads();
    int base = blockIdx.x * 4096;
    for (int k = 0; k < 16; ++k) {
        int d = ei[N_EDGES + base + k * 256 + t];
        atomicAdd(&hh[d >> 10], 1);
    }
    __syncthreads();
    int c = hh[t];
    bb[t] = c ? atomicAdd(&bcur[t], c) : 0;
    hh[t] = 0;
    __syncthreads();
    for (int k = 0; k < 16; ++k) {
        int e = base + k * 256 + t;
        int d = ei[N_EDGES + e], s = ei[e];
        int b = d >> 10;
        int r = atomicAdd(&hh[b], 1);
        pairs[bb[b] + r] = make_int2(s, d);
    }
}

// one block per bucket: count per dst, scan, write deg/offs coalesced,
// then rank edges in LDS and write csr_src into a private 32-KB window.
__global__ __launch_bounds__(256) void group_k(const int2* __restrict__ pairs,
                                               const int* __restrict__ bbase,
                                               int* __restrict__ deg,
                                               int* __restrict__ offs,
                                               int* __restrict__ csr_src) {
    __shared__ int cnt[1024];
    __shared__ int part[256];
    int b = blockIdx.x, t = threadIdx.x;
    int lo = bbase[b], hi = bbase[b + 1];
    for (int i = t; i < 1024; i += 256) cnt[i] = 0;
    __syncthreads();
    for (int j = lo + t; j < hi; j += 256)
        atomicAdd(&cnt[pairs[j].y & 1023], 1);
    __syncthreads();
    int c0 = cnt[4*t], c1 = cnt[4*t+1], c2 = cnt[4*t+2], c3 = cnt[4*t+3];
    int sum = c0 + c1 + c2 + c3;
    part[t] = sum;
    __syncthreads();
    for (int off = 1; off < 256; off <<= 1) {
        int a = (t >= off) ? part[t - off] : 0;
        __syncthreads();
        part[t] += a;
        __syncthreads();
    }
    int ex = part[t] - sum;          // exclusive offset of this thread's 4 dsts
    int dbase = b << 10;
    int o0 = ex, o1 = ex + c0, o2 = ex + c0 + c1, o3 = ex + c0 + c1 + c2;
    deg[dbase + 4*t+0] = c0;  offs[dbase + 4*t+0] = lo + o0;
    deg[dbase + 4*t+1] = c1;  offs[dbase + 4*t+1] = lo + o1;
    deg[dbase + 4*t+2] = c2;  offs[dbase + 4*t+2] = lo + o2;
    deg[dbase + 4*t+3] = c3;  offs[dbase + 4*t+3] = lo + o3;
    cnt[4*t+0] = o0; cnt[4*t+1] = o1; cnt[4*t+2] = o2; cnt[4*t+3] = o3;
    __syncthreads();
    for (int j = lo + t; j < hi; j += 256) {
        int2 p = pairs[j];
        int r = atomicAdd(&cnt[p.y & 1023], 1);
        csr_src[lo + r] = p.x;
    }
}

// ---- alpha precompute: alpha[n][ch] = b1 + W1x*x_n + W1r . pos_n  (fp32) ----
__global__ __launch_bounds__(256) void alpha_k(const float* __restrict__ x,
                                               const float* __restrict__ pos,
                                               const float* __restrict__ W1,
                                               const float* __restrict__ b1,
                                               float* __restrict__ alpha) {
    int t = blockIdx.x * 256 + threadIdx.x;   // N*16 threads
    int n = t >> 4, ch = t & 15;
    float a = b1[ch] + W1[ch] * x[n]
            + W1[16 + ch] * pos[3*n] + W1[32 + ch] * pos[3*n+1] + W1[48 + ch] * pos[3*n+2];
    alpha[t] = a;
}

// ---- conv1 fused: gather-max alpha -> BN+ReLU -> h (in LDS) -> beta (fp16) ----
// wave = 4 nodes x 16 ch. 1024 blocks x 4 waves x 16 iters x 4 nodes = 262144.
#define C1_BLOCKS 1024
#define C1_ITERS  16
__global__ __launch_bounds__(256) void conv1_fused(
    const float* __restrict__ alpha, const float* __restrict__ pos,
    const int* __restrict__ offs, const int* __restrict__ deg,
    const int* __restrict__ csr_src,
    const float* __restrict__ W1,
    const float* __restrict__ mean, const float* __restrict__ var,
    const float* __restrict__ gamma, const float* __restrict__ beta_bn,
    const float* __restrict__ W2, const float* __restrict__ b2,
    __half* __restrict__ beta)
{
    __shared__ float w2s[608], b2s[32];
    __shared__ float hs[4][64];      // per wave: 4 nodes x 16
    __shared__ float ps[4][12];      // per wave: 4 nodes x 3
    __shared__ int   ns[4][4];
    for (int i = threadIdx.x; i < 608; i += 256) w2s[i] = W2[i];
    if (threadIdx.x < 32) b2s[threadIdx.x] = b2[threadIdx.x];

    const int wave = threadIdx.x >> 6;
    const int lane = threadIdx.x & 63;
    const int q    = lane >> 4;      // node within wave
    const int ch   = lane & 15;
    const int c    = lane & 31;      // beta-phase channel
    const int nlo  = lane >> 5;      // beta-phase node offset

    float wrx = W1[16 + ch], wry = W1[32 + ch], wrz = W1[48 + ch];
    float sc = gamma[ch] * rsqrtf(var[ch] + EPS_BN);
    float sh = beta_bn[ch] - mean[ch] * sc;
    __syncthreads();

    for (int it = 0; it < C1_ITERS; ++it) {
        int task = (it * 4 + wave) * C1_BLOCKS + blockIdx.x;
        int n = task * 4 + q;
        int start = offs[n], dg = deg[n];
        float px = pos[3*n], py = pos[3*n+1], pz = pos[3*n+2];
        float m = -INFINITY;
        int j = start, end = start + dg;
        for (; j + 2 <= end; j += 2) {
            int s0 = csr_src[j], s1 = csr_src[j+1];
            float a0 = alpha[s0 * 16 + ch];
            float a1 = alpha[s1 * 16 + ch];
            m = fmaxf(m, fmaxf(a0, a1));
        }
        if (j < end) m = fmaxf(m, alpha[csr_src[j] * 16 + ch]);
        float v = dg ? (m - (wrx*px + wry*py + wrz*pz)) : 0.0f;
        float h = fmaxf(v * sc + sh, 0.0f);
        hs[wave][q * 16 + ch] = h;
        if (ch == 0) ns[wave][q] = n;
        if (ch < 3) ps[wave][q * 3 + ch] = (ch == 0) ? px : ((ch == 1) ? py : pz);
        __syncthreads();
        // beta phase: 4 nodes x 32 ch with 64 lanes -> 2 passes
#pragma unroll
        for (int p = 0; p < 2; ++p) {
            int nl = nlo + p * 2;
            float bsv = b2s[c];
#pragma unroll
            for (int k = 0; k < 16; ++k)
                bsv += w2s[k * 32 + c] * hs[wave][nl * 16 + k];
            float qx = ps[wave][nl*3], qy = ps[wave][nl*3+1], qz = ps[wave][nl*3+2];
            bsv += w2s[16*32 + c] * qx + w2s[17*32 + c] * qy + w2s[18*32 + c] * qz;
            beta[(size_t)ns[wave][nl] * 32 + c] = __float2half(bsv);
        }
        __syncthreads();
    }
}

// ---- conv2 + pool: gather-max beta(fp16) -> BN+ReLU -> voxel pool ----
// wave = 2 nodes x 32 ch. 2048 blocks x 4 waves x 16 iters x 2 nodes = 262144.
#define C2_BLOCKS 2048
#define C2_ITERS  16
__global__ __launch_bounds__(256) void conv2_pool(
    const __half* __restrict__ beta, const float* __restrict__ pos,
    const int* __restrict__ offs, const int* __restrict__ deg,
    const int* __restrict__ csr_src,
    const float* __restrict__ W2,
    const float* __restrict__ mean, const float* __restrict__ var,
    const float* __restrict__ gamma, const float* __restrict__ beta_bn,
    unsigned* __restrict__ pool)
{
    __shared__ unsigned lpool[2048];
    for (int i = threadIdx.x; i < 2048; i += 256) lpool[i] = 0u;
    __syncthreads();

    const int wave = threadIdx.x >> 6;
    const int lane = threadIdx.x & 63;
    const int half = lane >> 5;
    const int ch   = lane & 31;

    float wrx = W2[16*32 + ch], wry = W2[17*32 + ch], wrz = W2[18*32 + ch];
    float sc = gamma[ch] * rsqrtf(var[ch] + EPS_BN);
    float sh = beta_bn[ch] - mean[ch] * sc;

    for (int it = 0; it < C2_ITERS; ++it) {
        int task = (it * 4 + wave) * C2_BLOCKS + blockIdx.x;
        int n = task * 2 + half;
        int start = offs[n], dg = deg[n];
        float px = pos[3*n], py = pos[3*n+1], pz = pos[3*n+2];
        float m = -INFINITY;
        int j = start, end = start + dg;
        for (; j + 2 <= end; j += 2) {
            int s0 = csr_src[j], s1 = csr_src[j+1];
            float b0 = __half2float(beta[(size_t)s0 * 32 + ch]);
            float b1 = __half2float(beta[(size_t)s1 * 32 + ch]);
            m = fmaxf(m, fmaxf(b0, b1));
        }
        if (j < end) m = fmaxf(m, __half2float(beta[(size_t)csr_src[j] * 32 + ch]));
        float v = dg ? (m - (wrx*px + wry*py + wrz*pz)) : 0.0f;
        float y = fmaxf(v * sc + sh, 0.0f);
        int gx = (int)floorf(px * (1.0f/16.0f));
        int gy = (int)floorf(py * (1.0f/16.0f));
        int cl = min(max(gx + gy * 8, 0), 63);
        atomicMax(&lpool[cl * 32 + ch], enc(y));
    }
    __syncthreads();
    // flush: skip atomics that cannot improve (stale reads <= current: safe)
    for (int i = threadIdx.x; i < 2048; i += 256) {
        unsigned u = lpool[i];
        if (u > pool[i]) atomicMax(&pool[i], u);
    }
}

__global__ __launch_bounds__(256) void pool_decode(const unsigned* __restrict__ pool,
                                                   float* __restrict__ out) {
    int i = blockIdx.x * 256 + threadIdx.x;   // 2048
    unsigned u = pool[i];
    out[i] = (u == 0u) ? 0.0f : dec(u);
}

extern "C" void kernel_launch(void* const* d_in, const int* in_sizes, int n_in,
                              void* d_out, int out_size, void* d_ws, size_t ws_size,
                              hipStream_t stream) {
    const float* x    = (const float*)d_in[0];
    const float* pos  = (const float*)d_in[1];
    const int*   ei   = (const int*)d_in[2];
    const float* W1   = (const float*)d_in[3];
    const float* b1   = (const float*)d_in[4];
    const float* bn1m = (const float*)d_in[5];
    const float* bn1v = (const float*)d_in[6];
    const float* bn1w = (const float*)d_in[7];
    const float* bn1b = (const float*)d_in[8];
    const float* W2   = (const float*)d_in[9];
    const float* b2   = (const float*)d_in[10];
    const float* bn2m = (const float*)d_in[11];
    const float* bn2v = (const float*)d_in[12];
    const float* bn2w = (const float*)d_in[13];
    const float* bn2b = (const float*)d_in[14];

    unsigned* pool = (unsigned*)d_ws;                    // 2048 [zeroed]
    int* btot      = (int*)(pool + 2048);                // 256  [zeroed]
    int* bbase     = btot + 256;                         // 257 (+pad to 272)
    int* bcur      = bbase + 272;                        // 256
    int* deg       = bcur + 256;                         // N
    int* offs      = deg + N_NODES;                      // N
    int* csr_src   = offs + N_NODES;                     // 8N
    int2* pairs    = (int2*)(csr_src + N_EDGES);         // E int2 = 16N ints
    float* alpha   = (float*)pairs;                      // 16N fp32 (reuses pairs after group_k)
    __half* beta   = (__half*)((int*)pairs + (size_t)N_NODES * 16); // 32N fp16 = 16N ints

    hipMemsetAsync(d_ws, 0, (size_t)(2048 + 256) * 4, stream);

    hist_bucket <<<N_EDGES/4096, 256, 0, stream>>>(ei, btot);
    scan256_k   <<<1, 256, 0, stream>>>(btot, bbase, bcur);
    part_k      <<<N_EDGES/4096, 256, 0, stream>>>(ei, bcur, pairs);
    group_k     <<<256, 256, 0, stream>>>(pairs, bbase, deg, offs, csr_src);
    alpha_k     <<<N_NODES*16/256, 256, 0, stream>>>(x, pos, W1, b1, alpha);
    conv1_fused <<<C1_BLOCKS, 256, 0, stream>>>(alpha, pos, offs, deg, csr_src,
                                                W1, bn1m, bn1v, bn1w, bn1b, W2, b2, beta);
    conv2_pool  <<<C2_BLOCKS, 256, 0, stream>>>(beta, pos, offs, deg, csr_src,
                                                W2, bn2m, bn2v, bn2w, bn2b, pool);
    pool_decode <<<8, 256, 0, stream>>>(pool, (float*)d_out);
}

// Round 9
// 330.938 us; speedup vs baseline: 5.8873x; 1.0943x over previous
//
#include <hip/hip_runtime.h>
#include <hip/hip_fp16.h>

#define N_NODES 262144
#define N_EDGES 2097152
#define EPS_BN 1e-5f

// Monotone float<->uint encoding: preserves order, 0 is a sentinel below everything.
__device__ __forceinline__ unsigned enc(float f) {
    unsigned u = __float_as_uint(f);
    return (u & 0x80000000u) ? ~u : (u | 0x80000000u);
}
__device__ __forceinline__ float dec(unsigned u) {
    unsigned b = (u & 0x80000000u) ? (u & 0x7FFFFFFFu) : ~u;
    return __uint_as_float(b);
}

// ---- CSR build: two-level bucket grouping (no global value scatter) ----
// bucket b = dst >> 10  (256 buckets x 1024 dsts; N = 256*1024 exactly)
// packed pair = src | (dst&1023)<<18   (src < 2^18)

__global__ __launch_bounds__(256) void hist_bucket(const int* __restrict__ ei,
                                                   int* __restrict__ btot) {
    __shared__ int hh[256];
    int t = threadIdx.x;
    hh[t] = 0;
    __syncthreads();
    int base = blockIdx.x * 4096;
    for (int k = 0; k < 16; ++k) {
        int d = ei[N_EDGES + base + k * 256 + t];
        atomicAdd(&hh[d >> 10], 1);
    }
    __syncthreads();
    if (hh[t]) atomicAdd(&btot[t], hh[t]);
}

__global__ __launch_bounds__(256) void scan256_k(const int* __restrict__ btot,
                                                 int* __restrict__ bbase,
                                                 int* __restrict__ bcur) {
    __shared__ int s[256];
    int t = threadIdx.x;
    int v = btot[t];
    s[t] = v;
    __syncthreads();
    for (int off = 1; off < 256; off <<= 1) {
        int a = (t >= off) ? s[t - off] : 0;
        __syncthreads();
        s[t] += a;
        __syncthreads();
    }
    bbase[t] = s[t] - v;
    bcur[t]  = s[t] - v;
    if (t == 255) bbase[256] = s[255];
}

// partition edges into coarse buckets; each block writes runs per bucket (packed 4B)
__global__ __launch_bounds__(256) void part_k(const int* __restrict__ ei,
                                              int* __restrict__ bcur,
                                              unsigned* __restrict__ pairs) {
    __shared__ int hh[256], bb[256];
    int t = threadIdx.x;
    hh[t] = 0;
    __syncthreads();
    int base = blockIdx.x * 4096;
    for (int k = 0; k < 16; ++k) {
        int d = ei[N_EDGES + base + k * 256 + t];
        atomicAdd(&hh[d >> 10], 1);
    }
    __syncthreads();
    int c = hh[t];
    bb[t] = c ? atomicAdd(&bcur[t], c) : 0;
    hh[t] = 0;
    __syncthreads();
    for (int k = 0; k < 16; ++k) {
        int e = base + k * 256 + t;
        int d = ei[N_EDGES + e], s = ei[e];
        int b = d >> 10;
        int r = atomicAdd(&hh[b], 1);
        pairs[bb[b] + r] = (unsigned)s | ((unsigned)(d & 1023) << 18);
    }
}

// one block per bucket: count per dst, scan, write deg/offs coalesced,
// then rank edges in LDS and write csr_src into a private 32-KB window.
__global__ __launch_bounds__(256) void group_k(const unsigned* __restrict__ pairs,
                                               const int* __restrict__ bbase,
                                               int* __restrict__ deg,
                                               int* __restrict__ offs,
                                               int* __restrict__ csr_src) {
    __shared__ int cnt[1024];
    __shared__ int part[256];
    int b = blockIdx.x, t = threadIdx.x;
    int lo = bbase[b], hi = bbase[b + 1];
    for (int i = t; i < 1024; i += 256) cnt[i] = 0;
    __syncthreads();
    for (int j = lo + t; j < hi; j += 256)
        atomicAdd(&cnt[pairs[j] >> 18], 1);
    __syncthreads();
    int c0 = cnt[4*t], c1 = cnt[4*t+1], c2 = cnt[4*t+2], c3 = cnt[4*t+3];
    int sum = c0 + c1 + c2 + c3;
    part[t] = sum;
    __syncthreads();
    for (int off = 1; off < 256; off <<= 1) {
        int a = (t >= off) ? part[t - off] : 0;
        __syncthreads();
        part[t] += a;
        __syncthreads();
    }
    int ex = part[t] - sum;
    int dbase = b << 10;
    int o0 = ex, o1 = ex + c0, o2 = ex + c0 + c1, o3 = ex + c0 + c1 + c2;
    deg[dbase + 4*t+0] = c0;  offs[dbase + 4*t+0] = lo + o0;
    deg[dbase + 4*t+1] = c1;  offs[dbase + 4*t+1] = lo + o1;
    deg[dbase + 4*t+2] = c2;  offs[dbase + 4*t+2] = lo + o2;
    deg[dbase + 4*t+3] = c3;  offs[dbase + 4*t+3] = lo + o3;
    cnt[4*t+0] = o0; cnt[4*t+1] = o1; cnt[4*t+2] = o2; cnt[4*t+3] = o3;
    __syncthreads();
    for (int j = lo + t; j < hi; j += 256) {
        unsigned p = pairs[j];
        int r = atomicAdd(&cnt[p >> 18], 1);
        csr_src[lo + r] = (int)(p & 0x3FFFFu);
    }
}

// ---- alpha precompute: alpha[n][ch] = b1 + W1x*x_n + W1r . pos_n  (fp32) ----
__global__ __launch_bounds__(256) void alpha_k(const float* __restrict__ x,
                                               const float* __restrict__ pos,
                                               const float* __restrict__ W1,
                                               const float* __restrict__ b1,
                                               float* __restrict__ alpha) {
    int t = blockIdx.x * 256 + threadIdx.x;   // N*16 threads
    int n = t >> 4, ch = t & 15;
    float a = b1[ch] + W1[ch] * x[n]
            + W1[16 + ch] * pos[3*n] + W1[32 + ch] * pos[3*n+1] + W1[48 + ch] * pos[3*n+2];
    alpha[t] = a;
}

// ---- conv1 fused: 1-wave blocks. wave = 4 edges x 16 ch per node. ----
// 8192 blocks x 32 iters = 262144 nodes.
#define C1_BLOCKS 8192
#define C1_ITERS  32
__global__ __launch_bounds__(64) void conv1_fused(
    const float* __restrict__ alpha, const float* __restrict__ pos,
    const int* __restrict__ offs, const int* __restrict__ deg,
    const int* __restrict__ csr_src,
    const float* __restrict__ W1,
    const float* __restrict__ mean, const float* __restrict__ var,
    const float* __restrict__ gamma, const float* __restrict__ beta_bn,
    const float* __restrict__ W2, const float* __restrict__ b2,
    __half* __restrict__ beta)
{
    __shared__ float w2s[608], b2s[32], hs[16];
    int lane = threadIdx.x;
    int e4 = lane >> 4, ch = lane & 15;
    for (int i = lane; i < 608; i += 64) w2s[i] = W2[i];
    if (lane < 32) b2s[lane] = b2[lane];
    float wrx = W1[16 + ch], wry = W1[32 + ch], wrz = W1[48 + ch];
    float sc = gamma[ch] * rsqrtf(var[ch] + EPS_BN);
    float sh = beta_bn[ch] - mean[ch] * sc;
    __syncthreads();

    int n = blockIdx.x;                       // task(0)
    int cs = offs[n], cd = deg[n];
    float cx = pos[3*n], cy = pos[3*n+1], cz = pos[3*n+2];
    for (int it = 0; it < C1_ITERS; ++it) {
        int nt = (it + 1 < C1_ITERS) ? (it + 1) * C1_BLOCKS + blockIdx.x : n;
        int ns_ = offs[nt], nd_ = deg[nt];    // prefetch next task (hidden by edge loop)
        float nx = pos[3*nt], ny = pos[3*nt+1], nz = pos[3*nt+2];

        float m = -INFINITY;
        int end = cs + cd;
        int j = cs + e4;
        for (; j + 4 < end; j += 8) {         // 2 edges per lane-group in flight
            int s0 = csr_src[j], s1 = csr_src[j + 4];
            float a0 = alpha[s0 * 16 + ch];
            float a1 = alpha[s1 * 16 + ch];
            m = fmaxf(m, fmaxf(a0, a1));
        }
        if (j < end) m = fmaxf(m, alpha[csr_src[j] * 16 + ch]);
        m = fmaxf(m, __shfl_xor(m, 16));
        m = fmaxf(m, __shfl_xor(m, 32));
        float v = cd ? (m - (wrx*cx + wry*cy + wrz*cz)) : 0.0f;
        float h = fmaxf(v * sc + sh, 0.0f);
        if (lane < 16) hs[lane] = h;
        __syncthreads();                       // 1-wave block: cheap
        if (lane < 32) {
            float bsv = b2s[lane];
#pragma unroll
            for (int k = 0; k < 16; ++k) bsv += w2s[k * 32 + lane] * hs[k];
            bsv += w2s[512 + lane] * cx + w2s[544 + lane] * cy + w2s[576 + lane] * cz;
            beta[n * 32 + lane] = __float2half(bsv);
        }
        __syncthreads();
        n = nt; cs = ns_; cd = nd_; cx = nx; cy = ny; cz = nz;
    }
}

// ---- conv2 + pool: wave = 2 edges x 32 ch per node, shfl-merge halves. ----
// 2048 blocks x 4 waves x 32 iters = 262144 nodes.
#define C2_BLOCKS 2048
#define C2_ITERS  32
__global__ __launch_bounds__(256) void conv2_pool(
    const __half* __restrict__ beta, const float* __restrict__ pos,
    const int* __restrict__ offs, const int* __restrict__ deg,
    const int* __restrict__ csr_src,
    const float* __restrict__ W2,
    const float* __restrict__ mean, const float* __restrict__ var,
    const float* __restrict__ gamma, const float* __restrict__ beta_bn,
    unsigned* __restrict__ pool)
{
    __shared__ unsigned lpool[2048];
    for (int i = threadIdx.x; i < 2048; i += 256) lpool[i] = 0u;
    __syncthreads();

    const int wave = threadIdx.x >> 6;
    const int lane = threadIdx.x & 63;
    const int e2   = lane >> 5;
    const int ch   = lane & 31;

    float wrx = W2[16*32 + ch], wry = W2[17*32 + ch], wrz = W2[18*32 + ch];
    float sc = gamma[ch] * rsqrtf(var[ch] + EPS_BN);
    float sh = beta_bn[ch] - mean[ch] * sc;

    int n = wave * C2_BLOCKS + blockIdx.x;    // task(0)
    int cs = offs[n], cd = deg[n];
    float cx = pos[3*n], cy = pos[3*n+1], cz = pos[3*n+2];
    for (int it = 0; it < C2_ITERS; ++it) {
        int nt = (it + 1 < C2_ITERS) ? ((it + 1) * 4 + wave) * C2_BLOCKS + blockIdx.x : n;
        int ns_ = offs[nt], nd_ = deg[nt];
        float nx = pos[3*nt], ny = pos[3*nt+1], nz = pos[3*nt+2];

        float m = -INFINITY;
        int end = cs + cd;
        int j = cs + e2;
        for (; j + 2 < end; j += 4) {          // 2 edges per half in flight
            int s0 = csr_src[j], s1 = csr_src[j + 2];
            float b0 = __half2float(beta[s0 * 32 + ch]);
            float b1 = __half2float(beta[s1 * 32 + ch]);
            m = fmaxf(m, fmaxf(b0, b1));
        }
        if (j < end) m = fmaxf(m, __half2float(beta[csr_src[j] * 32 + ch]));
        m = fmaxf(m, __shfl_xor(m, 32));
        float v = cd ? (m - (wrx*cx + wry*cy + wrz*cz)) : 0.0f;
        float y = fmaxf(v * sc + sh, 0.0f);
        int gx = (int)floorf(cx * (1.0f/16.0f));
        int gy = (int)floorf(cy * (1.0f/16.0f));
        int cl = min(max(gx + gy * 8, 0), 63);
        if (e2 == 0) atomicMax(&lpool[cl * 32 + ch], enc(y));
        n = nt; cs = ns_; cd = nd_; cx = nx; cy = ny; cz = nz;
    }
    __syncthreads();
    // flush: skip atomics that cannot improve (stale reads <= current: safe)
    for (int i = threadIdx.x; i < 2048; i += 256) {
        unsigned u = lpool[i];
        if (u > pool[i]) atomicMax(&pool[i], u);
    }
}

__global__ __launch_bounds__(256) void pool_decode(const unsigned* __restrict__ pool,
                                                   float* __restrict__ out) {
    int i = blockIdx.x * 256 + threadIdx.x;   // 2048
    unsigned u = pool[i];
    out[i] = (u == 0u) ? 0.0f : dec(u);
}

extern "C" void kernel_launch(void* const* d_in, const int* in_sizes, int n_in,
                              void* d_out, int out_size, void* d_ws, size_t ws_size,
                              hipStream_t stream) {
    const float* x    = (const float*)d_in[0];
    const float* pos  = (const float*)d_in[1];
    const int*   ei   = (const int*)d_in[2];
    const float* W1   = (const float*)d_in[3];
    const float* b1   = (const float*)d_in[4];
    const float* bn1m = (const float*)d_in[5];
    const float* bn1v = (const float*)d_in[6];
    const float* bn1w = (const float*)d_in[7];
    const float* bn1b = (const float*)d_in[8];
    const float* W2   = (const float*)d_in[9];
    const float* b2   = (const float*)d_in[10];
    const float* bn2m = (const float*)d_in[11];
    const float* bn2v = (const float*)d_in[12];
    const float* bn2w = (const float*)d_in[13];
    const float* bn2b = (const float*)d_in[14];

    unsigned* pool = (unsigned*)d_ws;                    // 2048 [zeroed]
    int* btot      = (int*)(pool + 2048);                // 256  [zeroed]
    int* bbase     = btot + 256;                         // 257 (+pad to 272)
    int* bcur      = bbase + 272;                        // 256
    int* deg       = bcur + 256;                         // N
    int* offs      = deg + N_NODES;                      // N
    int* csr_src   = offs + N_NODES;                     // 8N
    unsigned* pairs = (unsigned*)(csr_src + N_EDGES);    // 8N packed (dead after group_k)
    float* alpha   = (float*)pairs;                      // 16N fp32 (reuses pairs region)
    __half* beta   = (__half*)((int*)pairs + (size_t)N_NODES * 16); // 32N fp16

    hipMemsetAsync(d_ws, 0, (size_t)(2048 + 256) * 4, stream);

    hist_bucket <<<N_EDGES/4096, 256, 0, stream>>>(ei, btot);
    scan256_k   <<<1, 256, 0, stream>>>(btot, bbase, bcur);
    part_k      <<<N_EDGES/4096, 256, 0, stream>>>(ei, bcur, pairs);
    group_k     <<<256, 256, 0, stream>>>(pairs, bbase, deg, offs, csr_src);
    alpha_k     <<<N_NODES*16/256, 256, 0, stream>>>(x, pos, W1, b1, alpha);
    conv1_fused <<<C1_BLOCKS, 64, 0, stream>>>(alpha, pos, offs, deg, csr_src,
                                               W1, bn1m, bn1v, bn1w, bn1b, W2, b2, beta);
    conv2_pool  <<<C2_BLOCKS, 256, 0, stream>>>(beta, pos, offs, deg, csr_src,
                                                W2, bn2m, bn2v, bn2w, bn2b, pool);
    pool_decode <<<8, 256, 0, stream>>>(pool, (float*)d_out);
}